// Round 12
// baseline (1494.854 us; speedup 1.0000x reference)
//
#include <hip/hip_runtime.h>
#include <hip/hip_cooperative_groups.h>
#include <cstdint>
#include <cstddef>

namespace cg = cooperative_groups;

#define TT 64
#define BB 32
#define SS 256
#define DH 512
#define VV 32000
#define NROWS 2048   // T*B
#define G4 2048      // 4*DH
#define NBLK_SCAN 256
#define NLEAF 8
#define LEAF_TARGET (NBLK_SCAN / NLEAF)   // 32 arrivals per leaf

typedef __attribute__((ext_vector_type(8))) short short8;
typedef __attribute__((ext_vector_type(4))) float f32x4;

__device__ __forceinline__ unsigned short f2bf(float x) {
    unsigned u = __float_as_uint(x);
    u += 0x7FFFu + ((u >> 16) & 1u);   // RNE
    return (unsigned short)(u >> 16);
}

__device__ __forceinline__ void gload_lds16(const void* g, void* l) {
    __builtin_amdgcn_global_load_lds(
        (const __attribute__((address_space(1))) unsigned int*)g,
        (__attribute__((address_space(3))) unsigned int*)l, 16, 0, 0);
}

// coherent (agent-scope) dword store -- proven cross-XCD exchange primitive
__device__ __forceinline__ void coh_store(float* p, float v) {
    __hip_atomic_store(p, v, __ATOMIC_RELAXED, __HIP_MEMORY_SCOPE_AGENT);
}

// ---------------- prep kernels ----------------
__global__ void k_convert_bf16(const float* __restrict__ src,
                               unsigned short* __restrict__ dst, int n4) {
    int i = blockIdx.x * blockDim.x + threadIdx.x;
    int stride = gridDim.x * blockDim.x;
    for (; i < n4; i += stride) {
        float4 v = ((const float4*)src)[i];
        ushort4 o;
        o.x = f2bf(v.x); o.y = f2bf(v.y); o.z = f2bf(v.z); o.w = f2bf(v.w);
        ((ushort4*)dst)[i] = o;
    }
}

__global__ void k_gather_embed32(const int* __restrict__ xseq,
                                 const float* __restrict__ emb,
                                 float* __restrict__ ef) {
    int r = blockIdx.x;
    int tok = xseq[r];
    const float4* s = (const float4*)(emb + (size_t)tok * DH);
    float4* d = (float4*)(ef + (size_t)r * DH);
    for (int i = threadIdx.x; i < DH / 4; i += blockDim.x) d[i] = s[i];
}

// zero barrier counters (h0 needs no transpose: exchange is [b][j] = h0 layout)
__global__ void k_scan_init(int* __restrict__ cnt) {
    int i = blockIdx.x * blockDim.x + threadIdx.x;
    if (i < TT * 128) cnt[i] = 0;
}

// ---------------- fp32 SGEMM: Ct[N,M] = (A[M,K] @ B[N,K]^T + b1 + b2)^T ----------
__global__ __launch_bounds__(256)
void k_sgemm_xpart(const float* __restrict__ A, const float* __restrict__ B,
                   const float* __restrict__ bias1, const float* __restrict__ bias2,
                   float* __restrict__ Ct, int M, int N, int K) {
    __shared__ float As[16][128];
    __shared__ float Bs[16][132];

    const int tid = threadIdx.x;
    const int tx = tid & 15, ty = tid >> 4;
    const int m0 = blockIdx.y * 128, n0 = blockIdx.x * 128;
    const int r = tid >> 1;
    const int c8 = (tid & 1) * 8;

    float acc[8][8] = {};

    for (int kt = 0; kt < K; kt += 16) {
        float4 a0 = *(const float4*)&A[(size_t)(m0 + r) * K + kt + c8];
        float4 a1 = *(const float4*)&A[(size_t)(m0 + r) * K + kt + c8 + 4];
        float4 b0 = *(const float4*)&B[(size_t)(n0 + r) * K + kt + c8];
        float4 b1 = *(const float4*)&B[(size_t)(n0 + r) * K + kt + c8 + 4];
        __syncthreads();
        As[c8 + 0][r] = a0.x; As[c8 + 1][r] = a0.y; As[c8 + 2][r] = a0.z; As[c8 + 3][r] = a0.w;
        As[c8 + 4][r] = a1.x; As[c8 + 5][r] = a1.y; As[c8 + 6][r] = a1.z; As[c8 + 7][r] = a1.w;
        Bs[c8 + 0][r] = b0.x; Bs[c8 + 1][r] = b0.y; Bs[c8 + 2][r] = b0.z; Bs[c8 + 3][r] = b0.w;
        Bs[c8 + 4][r] = b1.x; Bs[c8 + 5][r] = b1.y; Bs[c8 + 6][r] = b1.z; Bs[c8 + 7][r] = b1.w;
        __syncthreads();
#pragma unroll
        for (int kk = 0; kk < 16; ++kk) {
            float4 av0 = *(const float4*)&As[kk][ty * 8];
            float4 av1 = *(const float4*)&As[kk][ty * 8 + 4];
            float4 bv0 = *(const float4*)&Bs[kk][tx * 8];
            float4 bv1 = *(const float4*)&Bs[kk][tx * 8 + 4];
            float av[8] = {av0.x, av0.y, av0.z, av0.w, av1.x, av1.y, av1.z, av1.w};
            float bv[8] = {bv0.x, bv0.y, bv0.z, bv0.w, bv1.x, bv1.y, bv1.z, bv1.w};
#pragma unroll
            for (int i = 0; i < 8; ++i)
#pragma unroll
                for (int j = 0; j < 8; ++j)
                    acc[i][j] += av[i] * bv[j];
        }
    }
#pragma unroll
    for (int i = 0; i < 8; ++i) {
        int grow = m0 + ty * 8 + i;
#pragma unroll
        for (int j = 0; j < 8; ++j) {
            int col = n0 + tx * 8 + j;
            Ct[(size_t)col * M + grow] = acc[i][j] + bias1[col] + bias2[col];
        }
    }
}

// ---------------- MFMA GEMM: C[M,N] = A[M,K] @ B[N,K]^T (+epilogue) ----------------
template <int EPI>
__global__ __launch_bounds__(256)
void k_mfma_gemm(const unsigned short* __restrict__ A,
                 const unsigned short* __restrict__ B,
                 int M, int N, int K,
                 const float* __restrict__ bias,
                 float* __restrict__ Cf,
                 unsigned short* __restrict__ Cbf,
                 float* __restrict__ pm, float* __restrict__ ps) {
    __shared__ unsigned short A_s[128 * 64];
    __shared__ unsigned short B_s[128 * 64];
    __shared__ float part_m[2][128];
    __shared__ float part_s[2][128];

    const int tid = threadIdx.x;
    const int lane = tid & 63;
    const int wid = tid >> 6;
    const int wm = wid >> 1, wn = wid & 1;
    const int mrow0 = blockIdx.y * 128;
    const int ncol0 = blockIdx.x * 128;
    const int lr = lane & 15;
    const int lk = (lane >> 4) * 8;
    const int rw = (lane >> 4) * 4;

    f32x4 acc[4][4] = {};

    for (int kt = 0; kt < K; kt += 64) {
#pragma unroll
        for (int it = 0; it < 4; ++it) {
            int chunk = it * 256 + tid;
            int r = chunk >> 3;
            int c = (chunk & 7) * 8;
            gload_lds16(A + (size_t)(mrow0 + r) * K + kt + c, (void*)(A_s + chunk * 8));
            gload_lds16(B + (size_t)(ncol0 + r) * K + kt + c, (void*)(B_s + chunk * 8));
        }
        __syncthreads();
#pragma unroll
        for (int kk = 0; kk < 2; ++kk) {
            short8 afr[4], bfr[4];
#pragma unroll
            for (int i = 0; i < 4; ++i) {
                afr[i] = *(const short8*)&A_s[(wm * 64 + i * 16 + lr) * 64 + kk * 32 + lk];
                bfr[i] = *(const short8*)&B_s[(wn * 64 + i * 16 + lr) * 64 + kk * 32 + lk];
            }
#pragma unroll
            for (int mi = 0; mi < 4; ++mi)
#pragma unroll
                for (int ni = 0; ni < 4; ++ni)
                    acc[mi][ni] = __builtin_amdgcn_mfma_f32_16x16x32_bf16(
                        afr[mi], bfr[ni], acc[mi][ni], 0, 0, 0);
        }
        __syncthreads();
    }

    if constexpr (EPI == 1) {
#pragma unroll
        for (int ni = 0; ni < 4; ++ni) {
            int col = ncol0 + wn * 64 + ni * 16 + lr;
#pragma unroll
            for (int mi = 0; mi < 4; ++mi)
#pragma unroll
                for (int r = 0; r < 4; ++r) {
                    int grow = mrow0 + wm * 64 + mi * 16 + rw + r;
                    Cbf[(size_t)grow * N + col] = f2bf(tanhf(acc[mi][ni][r]));
                }
        }
    } else {
        float bv[4];
#pragma unroll
        for (int ni = 0; ni < 4; ++ni) bv[ni] = bias[ncol0 + wn * 64 + ni * 16 + lr];
#pragma unroll
        for (int mi = 0; mi < 4; ++mi) {
#pragma unroll
            for (int r = 0; r < 4; ++r) {
                int grow = mrow0 + wm * 64 + mi * 16 + rw + r;
                float v[4];
                float mx = -1e30f;
#pragma unroll
                for (int ni = 0; ni < 4; ++ni) {
                    v[ni] = acc[mi][ni][r] + bv[ni];
                    int col = ncol0 + wn * 64 + ni * 16 + lr;
                    Cf[(size_t)grow * N + col] = v[ni];
                    mx = fmaxf(mx, v[ni]);
                }
#pragma unroll
                for (int d = 1; d <= 8; d <<= 1) mx = fmaxf(mx, __shfl_xor(mx, d));
                float ssum = 0.f;
#pragma unroll
                for (int ni = 0; ni < 4; ++ni) ssum += __expf(v[ni] - mx);
#pragma unroll
                for (int d = 1; d <= 8; d <<= 1) ssum += __shfl_xor(ssum, d);
                if (lr == 0) {
                    int lrow = wm * 64 + mi * 16 + rw + r;
                    part_m[wn][lrow] = mx;
                    part_s[wn][lrow] = ssum;
                }
            }
        }
        __syncthreads();
        if (tid < 128) {
            float m0v = part_m[0][tid], m1v = part_m[1][tid];
            float mm = fmaxf(m0v, m1v);
            float ssum = part_s[0][tid] * __expf(m0v - mm) + part_s[1][tid] * __expf(m1v - mm);
            int grow = mrow0 + tid;
            pm[(size_t)grow * gridDim.x + blockIdx.x] = mm;
            ps[(size_t)grow * gridDim.x + blockIdx.x] = ssum;
        }
    }
}

// ---------------- LSTM scan: register-resident W, ks-split dot ------------------
// 256 blocks x 1024 threads: (jl = tid>>9) in 0..1 (jj = blk*2+jl),
// b = (tid>>4)&31, ks = tid&15 (k-slice of 32). W_hh held in REGISTERS
// (wreg[4][8] float4 = this thread's 4 gate rows, cols ks*32..+31) all 64 steps.
// h exchange buffers are [b][j] fp32 (= h0 native layout; no init transpose);
// coh_store + batched sc0sc1 loads + r5 parity + r11 leaf barrier (all proven).
// h staged in LDS as float4 tiles [b][r][ks] -> conflict-free b128 read/write.
__global__ __launch_bounds__(1024, 1)
void k_lstm_scan(const float* __restrict__ xpartT, const float* __restrict__ Whh,
                 const float* __restrict__ h0, const float* __restrict__ c0,
                 float* __restrict__ hTA, float* __restrict__ hTB,
                 float* __restrict__ Hall, unsigned short* __restrict__ catbuf,
                 float* __restrict__ hf, float* __restrict__ cf,
                 int* __restrict__ cnt) {
    __shared__ __align__(16) float h_lds[BB * DH];   // 64 KB, [b][r][ks] float4 tiles

    const int tid = threadIdx.x;
    const int jl = tid >> 9;             // 0..1
    const int b = (tid >> 4) & 31;
    const int ks = tid & 15;             // k-slice: cols ks*32 .. ks*32+31
    const int jj = blockIdx.x * 2 + jl;

    // --- prologue: this thread's W slice into registers (4 gates x 32 cols) ---
    f32x4 wreg[4][8];
#pragma unroll
    for (int g = 0; g < 4; ++g) {
        const float* wp = Whh + (size_t)(g * DH + jj) * DH + ks * 32;
#pragma unroll
        for (int r = 0; r < 8; ++r)
            wreg[g][r] = *(const f32x4*)(wp + r * 4);
    }

    float creg = c0[(size_t)b * DH + jj];   // used only by ks==0 lanes

    for (int t = 0; t < TT; ++t) {
        // xpart bias prefetch (cached loads; latency hides under stage drain)
        float xg0 = 0.f, xg1 = 0.f, xg2 = 0.f, xg3 = 0.f;
        if (ks == 0) {
            const float* xt = xpartT + (size_t)t * BB + b;
            xg0 = xt[(size_t)(0 * DH + jj) * NROWS];
            xg1 = xt[(size_t)(1 * DH + jj) * NROWS];
            xg2 = xt[(size_t)(2 * DH + jj) * NROWS];
            xg3 = xt[(size_t)(3 * DH + jj) * NROWS];
        }

        const float* hR = (t == 0) ? h0 : ((t & 1) ? hTA : hTB);   // r5 parity
        // ---- stage h: 4 coalesced uncached dwordx4 per thread -> LDS tiles ----
        {
            f32x4 v[4];
#pragma unroll
            for (int q = 0; q < 4; ++q)
                asm volatile("global_load_dwordx4 %0, %1, off sc0 sc1"
                             : "=&v"(v[q]) : "v"(hR + (q * 1024 + tid) * 4));
            asm volatile("s_waitcnt vmcnt(0)" ::: "memory");
            __builtin_amdgcn_sched_barrier(0);
#pragma unroll
            for (int q = 0; q < 4; ++q) {
                int f = q * 1024 + tid;          // global float4 index: b*128 + ks2*8 + r2
                int b2 = f >> 7;
                int ks2 = (f & 127) >> 3;
                int r2 = f & 7;
                *(f32x4*)&h_lds[((b2 * 8 + r2) * 16 + ks2) * 4] = v[q];
            }
        }
        __syncthreads();

        // ---- partial dot: 8 x (b128 read + 4x4 FMA), W from registers ----
        float a0 = 0.f, a1 = 0.f, a2 = 0.f, a3 = 0.f;
#pragma unroll
        for (int r = 0; r < 8; ++r) {
            f32x4 hv = *(const f32x4*)&h_lds[((b * 8 + r) * 16 + ks) * 4];
            a0 += wreg[0][r][0] * hv[0] + wreg[0][r][1] * hv[1]
                + wreg[0][r][2] * hv[2] + wreg[0][r][3] * hv[3];
            a1 += wreg[1][r][0] * hv[0] + wreg[1][r][1] * hv[1]
                + wreg[1][r][2] * hv[2] + wreg[1][r][3] * hv[3];
            a2 += wreg[2][r][0] * hv[0] + wreg[2][r][1] * hv[1]
                + wreg[2][r][2] * hv[2] + wreg[2][r][3] * hv[3];
            a3 += wreg[3][r][0] * hv[0] + wreg[3][r][1] * hv[1]
                + wreg[3][r][2] * hv[2] + wreg[3][r][3] * hv[3];
        }
        // reduce over ks (lane bits 0..3)
#pragma unroll
        for (int d = 1; d <= 8; d <<= 1) {
            a0 += __shfl_xor(a0, d);
            a1 += __shfl_xor(a1, d);
            a2 += __shfl_xor(a2, d);
            a3 += __shfl_xor(a3, d);
        }

        if (ks == 0) {
            float gi = a0 + xg0;
            float gf = a1 + xg1;
            float gg = a2 + xg2;
            float go = a3 + xg3;
            float si = 1.f / (1.f + __expf(-gi));
            float sf = 1.f / (1.f + __expf(-gf));
            float tg = tanhf(gg);
            float so = 1.f / (1.f + __expf(-go));
            creg = sf * creg + si * tg;
            float hn = so * tanhf(creg);
            float* wb = (t & 1) ? hTB : hTA;          // r5 writer parity
            coh_store(&wb[(size_t)b * DH + jj], hn);  // [b][j] layout
            int row = t * BB + b;
            Hall[(size_t)row * DH + jj] = hn;
            catbuf[(size_t)row * 1024 + jj] = f2bf(hn);
            if (t == TT - 1) {
                hf[(size_t)b * DH + jj] = hn;
                cf[(size_t)b * DH + jj] = creg;
            }
        }

        // ---- device barrier: 8-leaf arrival tree (r11-proven) ----
        __syncthreads();   // drains vmcnt before s_barrier -> h stores done
        if (tid == 0) {
            asm volatile("s_waitcnt vmcnt(0)" ::: "memory");
            __hip_atomic_fetch_add(&cnt[t * 128 + (blockIdx.x & (NLEAF - 1)) * 16], 1,
                                   __ATOMIC_RELAXED, __HIP_MEMORY_SCOPE_AGENT);
        }
        if (tid < NLEAF) {
            while (__hip_atomic_load(&cnt[t * 128 + tid * 16], __ATOMIC_RELAXED,
                                     __HIP_MEMORY_SCOPE_AGENT) < LEAF_TARGET) {
                __builtin_amdgcn_s_sleep(1);
            }
        }
        __syncthreads();
    }
}

// ---------------- attention: scores -> softmax -> wctx (per (b, 4 t's)) ----------------
__global__ __launch_bounds__(256)
void k_attn(const float* __restrict__ Hall, const float* __restrict__ ctx,
            unsigned short* __restrict__ catbuf) {
    __shared__ float h4[4][DH];
    __shared__ float p_lds[4][SS];
    __shared__ float l_lds[4];

    const int tid = threadIdx.x;
    const int b = blockIdx.x & 31;
    const int tg = blockIdx.x >> 5;

    for (int i = tid; i < 4 * DH / 4; i += 256) {
        int e = i * 4;
        int ti = e >> 9, k = e & 511;
        float4 v = *(const float4*)(Hall + ((size_t)((tg * 4 + ti) * BB + b)) * DH + k);
        h4[ti][k + 0] = v.x; h4[ti][k + 1] = v.y; h4[ti][k + 2] = v.z; h4[ti][k + 3] = v.w;
    }
    __syncthreads();

    {
        int s = tid;
        float acc[4] = {0.f, 0.f, 0.f, 0.f};
        const float4* cp = (const float4*)(ctx + ((size_t)b * SS + s) * DH);
        for (int kc = 0; kc < DH / 4; ++kc) {
            float4 cv = cp[kc];
#pragma unroll
            for (int i = 0; i < 4; ++i) {
                float4 hv = *(const float4*)&h4[i][kc * 4];
                acc[i] += cv.x * hv.x + cv.y * hv.y + cv.z * hv.z + cv.w * hv.w;
            }
        }
#pragma unroll
        for (int i = 0; i < 4; ++i) p_lds[i][s] = acc[i];
    }
    __syncthreads();

    {
        int w = tid >> 6, l = tid & 63;
        float v0 = p_lds[w][l], v1 = p_lds[w][l + 64];
        float v2 = p_lds[w][l + 128], v3 = p_lds[w][l + 192];
        float mx = fmaxf(fmaxf(v0, v1), fmaxf(v2, v3));
        for (int d = 1; d < 64; d <<= 1) mx = fmaxf(mx, __shfl_xor(mx, d));
        float e0 = __expf(v0 - mx), e1 = __expf(v1 - mx);
        float e2 = __expf(v2 - mx), e3 = __expf(v3 - mx);
        float ssum = e0 + e1 + e2 + e3;
        for (int d = 1; d < 64; d <<= 1) ssum += __shfl_xor(ssum, d);
        p_lds[w][l] = e0; p_lds[w][l + 64] = e1;
        p_lds[w][l + 128] = e2; p_lds[w][l + 192] = e3;
        if (l == 0) l_lds[w] = ssum;
    }
    __syncthreads();

    {
        int d0 = tid * 2;
        float accx[4], accy[4];
#pragma unroll
        for (int i = 0; i < 4; ++i) { accx[i] = 0.f; accy[i] = 0.f; }
        const float* cb = ctx + (size_t)b * SS * DH + d0;
        for (int s = 0; s < SS; ++s) {
            float2 cv = *(const float2*)(cb + (size_t)s * DH);
#pragma unroll
            for (int i = 0; i < 4; ++i) {
                float p = p_lds[i][s];
                accx[i] += p * cv.x;
                accy[i] += p * cv.y;
            }
        }
#pragma unroll
        for (int i = 0; i < 4; ++i) {
            float inv = 1.f / l_lds[i];
            int row = (tg * 4 + i) * BB + b;
            unsigned pack = (unsigned)f2bf(accx[i] * inv) | ((unsigned)f2bf(accy[i] * inv) << 16);
            *(unsigned*)&catbuf[(size_t)row * 1024 + DH + d0] = pack;
        }
    }
}

// ---------------- fused lse + subtract (one block per row) ----------------
__global__ __launch_bounds__(256)
void k_lsesub(float* __restrict__ logp, const float* __restrict__ pm,
              const float* __restrict__ ps, int nt) {
    __shared__ float sL;
    const int row = blockIdx.x;
    const int tid = threadIdx.x;
    if (tid < 64) {
        const float* pmr = pm + (size_t)row * nt;
        const float* psr = ps + (size_t)row * nt;
        float m = -1e30f;
        for (int i = tid; i < nt; i += 64) m = fmaxf(m, pmr[i]);
        for (int d = 1; d < 64; d <<= 1) m = fmaxf(m, __shfl_xor(m, d));
        float s = 0.f;
        for (int i = tid; i < nt; i += 64) s += psr[i] * __expf(pmr[i] - m);
        for (int d = 1; d < 64; d <<= 1) s += __shfl_xor(s, d);
        if (tid == 0) sL = m + logf(s);
    }
    __syncthreads();
    float L = sL;
    float4* p = (float4*)(logp + (size_t)row * VV);
    for (int i = tid; i < VV / 4; i += 256) {
        float4 v = p[i];
        v.x -= L; v.y -= L; v.z -= L; v.w -= L;
        p[i] = v;
    }
}

// ---------------- host launch ----------------
extern "C" void kernel_launch(void* const* d_in, const int* in_sizes, int n_in,
                              void* d_out, int out_size, void* d_ws, size_t ws_size,
                              hipStream_t stream) {
    const int*   xseq  = (const int*)d_in[0];
    const float* h0    = (const float*)d_in[1];
    const float* c0    = (const float*)d_in[2];
    const float* ctx   = (const float*)d_in[3];
    const float* emb   = (const float*)d_in[4];
    const float* Wih   = (const float*)d_in[5];
    const float* Whh   = (const float*)d_in[6];
    const float* bih   = (const float*)d_in[7];
    const float* bhh   = (const float*)d_in[8];
    const float* Wattn = (const float*)d_in[9];
    const float* Wout  = (const float*)d_in[10];
    const float* bout  = (const float*)d_in[11];
    float* out = (float*)d_out;

    char* wptr = (char*)d_ws;
    auto carve = [&](size_t bytes) {
        char* p = wptr;
        wptr += (bytes + 255) & ~(size_t)255;
        return p;
    };
    float*          xpartT  = (float*)carve((size_t)NROWS * G4 * 4);
    float*          Hall    = (float*)carve((size_t)NROWS * DH * 4);
    unsigned short* catbf   = (unsigned short*)carve((size_t)NROWS * 1024 * 2);
    unsigned short* outsbf  = (unsigned short*)carve((size_t)NROWS * DH * 2);
    float*          ef32    = (float*)carve((size_t)NROWS * DH * 4);
    unsigned short* Wattnbf = (unsigned short*)carve((size_t)DH * 1024 * 2);
    unsigned short* Woutbf  = (unsigned short*)carve((size_t)VV * DH * 2);
    float*          hTA     = (float*)carve((size_t)BB * DH * 4);
    float*          hTB     = (float*)carve((size_t)BB * DH * 4);
    int*            cnt     = (int*)carve((size_t)TT * 128 * 4);
    float*          pm      = (float*)carve((size_t)NROWS * 250 * 4);
    float*          ps      = (float*)carve((size_t)NROWS * 250 * 4);

    // prep
    k_convert_bf16<<<256, 256, 0, stream>>>(Wattn, Wattnbf, DH * 1024 / 4);
    k_convert_bf16<<<2048, 256, 0, stream>>>(Wout, Woutbf, VV * DH / 4);
    k_gather_embed32<<<NROWS, 128, 0, stream>>>(xseq, emb, ef32);
    k_scan_init<<<32, 256, 0, stream>>>(cnt);

    // x_part^T = (e @ W_ih^T + b_ih + b_hh)^T   -- full fp32, transposed write
    k_sgemm_xpart<<<dim3(16, 16), 256, 0, stream>>>(
        ef32, Wih, bih, bhh, xpartT, NROWS, G4, DH);

    // sequential LSTM scan (cooperative; register-W, leaf-tree barrier)
    {
        const float* a0 = xpartT; const float* a1 = Whh;
        const float* a2 = h0;     const float* a3 = c0;
        float* a4 = hTA; float* a5 = hTB; float* a6 = Hall;
        unsigned short* a7 = catbf;
        float* a8 = out + (size_t)NROWS * VV;           // hf
        float* a9 = a8 + BB * DH;                       // cf
        int* a10 = cnt;
        void* args[] = {&a0, &a1, &a2, &a3, &a4, &a5, &a6, &a7, &a8, &a9, &a10};
        hipLaunchCooperativeKernel((const void*)k_lstm_scan, dim3(NBLK_SCAN), dim3(1024),
                                   args, 0, stream);
    }

    // attention (parallel over all t,b)
    k_attn<<<512, 256, 0, stream>>>(Hall, ctx, catbf);

    // outs = tanh(cat @ W_attn^T)  -> bf16
    k_mfma_gemm<1><<<dim3(4, 16), 256, 0, stream>>>(
        catbf, Wattnbf, NROWS, DH, 1024, nullptr, nullptr, outsbf, nullptr, nullptr);

    // logits = outs @ W_out^T + b_out -> d_out (fp32) + softmax partials
    k_mfma_gemm<2><<<dim3(250, 16), 256, 0, stream>>>(
        outsbf, Woutbf, NROWS, VV, DH, bout, out, nullptr, pm, ps);

    // fused lse + in-place logp
    k_lsesub<<<NROWS, 256, 0, stream>>>(out, pm, ps, 250);
}

// Round 13
// 982.195 us; speedup vs baseline: 1.5220x; 1.5220x over previous
//
#include <hip/hip_runtime.h>
#include <hip/hip_cooperative_groups.h>
#include <cstdint>
#include <cstddef>

namespace cg = cooperative_groups;

#define TT 64
#define BB 32
#define SS 256
#define DH 512
#define VV 32000
#define NROWS 2048   // T*B
#define G4 2048      // 4*DH
#define NBLK_SCAN 256
#define NLEAF 8
#define LEAF_TARGET (NBLK_SCAN / NLEAF)   // 32 arrivals per leaf

typedef __attribute__((ext_vector_type(8))) short short8;
typedef __attribute__((ext_vector_type(4))) float f32x4;

__device__ __forceinline__ unsigned short f2bf(float x) {
    unsigned u = __float_as_uint(x);
    u += 0x7FFFu + ((u >> 16) & 1u);   // RNE
    return (unsigned short)(u >> 16);
}

__device__ __forceinline__ void gload_lds16(const void* g, void* l) {
    __builtin_amdgcn_global_load_lds(
        (const __attribute__((address_space(1))) unsigned int*)g,
        (__attribute__((address_space(3))) unsigned int*)l, 16, 0, 0);
}

// coherent (agent-scope) dword store -- proven cross-XCD exchange primitive
__device__ __forceinline__ void coh_store(float* p, float v) {
    __hip_atomic_store(p, v, __ATOMIC_RELAXED, __HIP_MEMORY_SCOPE_AGENT);
}

// ---------------- prep kernels ----------------
__global__ void k_convert_bf16(const float* __restrict__ src,
                               unsigned short* __restrict__ dst, int n4) {
    int i = blockIdx.x * blockDim.x + threadIdx.x;
    int stride = gridDim.x * blockDim.x;
    for (; i < n4; i += stride) {
        float4 v = ((const float4*)src)[i];
        ushort4 o;
        o.x = f2bf(v.x); o.y = f2bf(v.y); o.z = f2bf(v.z); o.w = f2bf(v.w);
        ((ushort4*)dst)[i] = o;
    }
}

__global__ void k_gather_embed32(const int* __restrict__ xseq,
                                 const float* __restrict__ emb,
                                 float* __restrict__ ef) {
    int r = blockIdx.x;
    int tok = xseq[r];
    const float4* s = (const float4*)(emb + (size_t)tok * DH);
    float4* d = (float4*)(ef + (size_t)r * DH);
    for (int i = threadIdx.x; i < DH / 4; i += blockDim.x) d[i] = s[i];
}

// zero barrier counters (exchange is [b][j] = h0 native layout, no transpose)
__global__ void k_scan_init(int* __restrict__ cnt) {
    int i = blockIdx.x * blockDim.x + threadIdx.x;
    if (i < TT * 128) cnt[i] = 0;
}

// ---------------- fp32 SGEMM: Ct[N,M] = (A[M,K] @ B[N,K]^T + b1 + b2)^T ----------
__global__ __launch_bounds__(256)
void k_sgemm_xpart(const float* __restrict__ A, const float* __restrict__ B,
                   const float* __restrict__ bias1, const float* __restrict__ bias2,
                   float* __restrict__ Ct, int M, int N, int K) {
    __shared__ float As[16][128];
    __shared__ float Bs[16][132];

    const int tid = threadIdx.x;
    const int tx = tid & 15, ty = tid >> 4;
    const int m0 = blockIdx.y * 128, n0 = blockIdx.x * 128;
    const int r = tid >> 1;
    const int c8 = (tid & 1) * 8;

    float acc[8][8] = {};

    for (int kt = 0; kt < K; kt += 16) {
        float4 a0 = *(const float4*)&A[(size_t)(m0 + r) * K + kt + c8];
        float4 a1 = *(const float4*)&A[(size_t)(m0 + r) * K + kt + c8 + 4];
        float4 b0 = *(const float4*)&B[(size_t)(n0 + r) * K + kt + c8];
        float4 b1 = *(const float4*)&B[(size_t)(n0 + r) * K + kt + c8 + 4];
        __syncthreads();
        As[c8 + 0][r] = a0.x; As[c8 + 1][r] = a0.y; As[c8 + 2][r] = a0.z; As[c8 + 3][r] = a0.w;
        As[c8 + 4][r] = a1.x; As[c8 + 5][r] = a1.y; As[c8 + 6][r] = a1.z; As[c8 + 7][r] = a1.w;
        Bs[c8 + 0][r] = b0.x; Bs[c8 + 1][r] = b0.y; Bs[c8 + 2][r] = b0.z; Bs[c8 + 3][r] = b0.w;
        Bs[c8 + 4][r] = b1.x; Bs[c8 + 5][r] = b1.y; Bs[c8 + 6][r] = b1.z; Bs[c8 + 7][r] = b1.w;
        __syncthreads();
#pragma unroll
        for (int kk = 0; kk < 16; ++kk) {
            float4 av0 = *(const float4*)&As[kk][ty * 8];
            float4 av1 = *(const float4*)&As[kk][ty * 8 + 4];
            float4 bv0 = *(const float4*)&Bs[kk][tx * 8];
            float4 bv1 = *(const float4*)&Bs[kk][tx * 8 + 4];
            float av[8] = {av0.x, av0.y, av0.z, av0.w, av1.x, av1.y, av1.z, av1.w};
            float bv[8] = {bv0.x, bv0.y, bv0.z, bv0.w, bv1.x, bv1.y, bv1.z, bv1.w};
#pragma unroll
            for (int i = 0; i < 8; ++i)
#pragma unroll
                for (int j = 0; j < 8; ++j)
                    acc[i][j] += av[i] * bv[j];
        }
    }
#pragma unroll
    for (int i = 0; i < 8; ++i) {
        int grow = m0 + ty * 8 + i;
#pragma unroll
        for (int j = 0; j < 8; ++j) {
            int col = n0 + tx * 8 + j;
            Ct[(size_t)col * M + grow] = acc[i][j] + bias1[col] + bias2[col];
        }
    }
}

// ---------------- MFMA GEMM: C[M,N] = A[M,K] @ B[N,K]^T (+epilogue) ----------------
template <int EPI>
__global__ __launch_bounds__(256)
void k_mfma_gemm(const unsigned short* __restrict__ A,
                 const unsigned short* __restrict__ B,
                 int M, int N, int K,
                 const float* __restrict__ bias,
                 float* __restrict__ Cf,
                 unsigned short* __restrict__ Cbf,
                 float* __restrict__ pm, float* __restrict__ ps) {
    __shared__ unsigned short A_s[128 * 64];
    __shared__ unsigned short B_s[128 * 64];
    __shared__ float part_m[2][128];
    __shared__ float part_s[2][128];

    const int tid = threadIdx.x;
    const int lane = tid & 63;
    const int wid = tid >> 6;
    const int wm = wid >> 1, wn = wid & 1;
    const int mrow0 = blockIdx.y * 128;
    const int ncol0 = blockIdx.x * 128;
    const int lr = lane & 15;
    const int lk = (lane >> 4) * 8;
    const int rw = (lane >> 4) * 4;

    f32x4 acc[4][4] = {};

    for (int kt = 0; kt < K; kt += 64) {
#pragma unroll
        for (int it = 0; it < 4; ++it) {
            int chunk = it * 256 + tid;
            int r = chunk >> 3;
            int c = (chunk & 7) * 8;
            gload_lds16(A + (size_t)(mrow0 + r) * K + kt + c, (void*)(A_s + chunk * 8));
            gload_lds16(B + (size_t)(ncol0 + r) * K + kt + c, (void*)(B_s + chunk * 8));
        }
        __syncthreads();
#pragma unroll
        for (int kk = 0; kk < 2; ++kk) {
            short8 afr[4], bfr[4];
#pragma unroll
            for (int i = 0; i < 4; ++i) {
                afr[i] = *(const short8*)&A_s[(wm * 64 + i * 16 + lr) * 64 + kk * 32 + lk];
                bfr[i] = *(const short8*)&B_s[(wn * 64 + i * 16 + lr) * 64 + kk * 32 + lk];
            }
#pragma unroll
            for (int mi = 0; mi < 4; ++mi)
#pragma unroll
                for (int ni = 0; ni < 4; ++ni)
                    acc[mi][ni] = __builtin_amdgcn_mfma_f32_16x16x32_bf16(
                        afr[mi], bfr[ni], acc[mi][ni], 0, 0, 0);
        }
        __syncthreads();
    }

    if constexpr (EPI == 1) {
#pragma unroll
        for (int ni = 0; ni < 4; ++ni) {
            int col = ncol0 + wn * 64 + ni * 16 + lr;
#pragma unroll
            for (int mi = 0; mi < 4; ++mi)
#pragma unroll
                for (int r = 0; r < 4; ++r) {
                    int grow = mrow0 + wm * 64 + mi * 16 + rw + r;
                    Cbf[(size_t)grow * N + col] = f2bf(tanhf(acc[mi][ni][r]));
                }
        }
    } else {
        float bv[4];
#pragma unroll
        for (int ni = 0; ni < 4; ++ni) bv[ni] = bias[ncol0 + wn * 64 + ni * 16 + lr];
#pragma unroll
        for (int mi = 0; mi < 4; ++mi) {
#pragma unroll
            for (int r = 0; r < 4; ++r) {
                int grow = mrow0 + wm * 64 + mi * 16 + rw + r;
                float v[4];
                float mx = -1e30f;
#pragma unroll
                for (int ni = 0; ni < 4; ++ni) {
                    v[ni] = acc[mi][ni][r] + bv[ni];
                    int col = ncol0 + wn * 64 + ni * 16 + lr;
                    Cf[(size_t)grow * N + col] = v[ni];
                    mx = fmaxf(mx, v[ni]);
                }
#pragma unroll
                for (int d = 1; d <= 8; d <<= 1) mx = fmaxf(mx, __shfl_xor(mx, d));
                float ssum = 0.f;
#pragma unroll
                for (int ni = 0; ni < 4; ++ni) ssum += __expf(v[ni] - mx);
#pragma unroll
                for (int d = 1; d <= 8; d <<= 1) ssum += __shfl_xor(ssum, d);
                if (lr == 0) {
                    int lrow = wm * 64 + mi * 16 + rw + r;
                    part_m[wn][lrow] = mx;
                    part_s[wn][lrow] = ssum;
                }
            }
        }
        __syncthreads();
        if (tid < 128) {
            float m0v = part_m[0][tid], m1v = part_m[1][tid];
            float mm = fmaxf(m0v, m1v);
            float ssum = part_s[0][tid] * __expf(m0v - mm) + part_s[1][tid] * __expf(m1v - mm);
            int grow = mrow0 + tid;
            pm[(size_t)grow * gridDim.x + blockIdx.x] = mm;
            ps[(size_t)grow * gridDim.x + blockIdx.x] = ssum;
        }
    }
}

// ---------------- LSTM scan: register-W ks-split dot, 512 threads ---------------
// 256 blocks x 512 threads: jl = tid>>8 (jj = blk*2+jl), bq = (tid>>4)&15
// (thread handles b = bq and bq+16), ks = tid&15 (cols ks*32..+31).
// W_hh in REGISTERS: wreg[4][8] f32x4 = 128 VGPR; __launch_bounds__(512,2)
// -> 256-VGPR cap, no spill (r12's 1024-thr variant spilled at the 128 cap).
// LDS tile [b][r][ks] with pad 17 float4/row: staging writes (r-fast lanes)
// and dot reads (ks-fast lanes) both hit distinct bank-quads -> no conflicts.
// Exchange [b][j] fp32 via coh_store + batched sc0sc1 loads; r5 parity;
// r11 8-leaf barrier. Cell math bit-identical to r10/r11.
__global__ __launch_bounds__(512, 2)
void k_lstm_scan(const float* __restrict__ xpartT, const float* __restrict__ Whh,
                 const float* __restrict__ h0, const float* __restrict__ c0,
                 float* __restrict__ hTA, float* __restrict__ hTB,
                 float* __restrict__ Hall, unsigned short* __restrict__ catbuf,
                 float* __restrict__ hf, float* __restrict__ cf,
                 int* __restrict__ cnt) {
    __shared__ __align__(16) float h_lds[BB * 8 * 17 * 4];   // 69.6 KB

    const int tid = threadIdx.x;
    const int jl = tid >> 8;             // 0..1
    const int bq = (tid >> 4) & 15;      // handles b = bq, bq+16
    const int ks = tid & 15;             // k-slice: cols ks*32 .. ks*32+31
    const int jj = blockIdx.x * 2 + jl;

    // --- prologue: this thread's W slice into registers (4 gates x 32 cols) ---
    f32x4 wreg[4][8];
#pragma unroll
    for (int g = 0; g < 4; ++g) {
        const float* wp = Whh + (size_t)(g * DH + jj) * DH + ks * 32;
#pragma unroll
        for (int r = 0; r < 8; ++r)
            wreg[g][r] = *(const f32x4*)(wp + r * 4);
    }

    float creg0 = c0[(size_t)bq * DH + jj];          // used only by ks==0
    float creg1 = c0[(size_t)(bq + 16) * DH + jj];

    for (int t = 0; t < TT; ++t) {
        // xpart bias prefetch (cached; latency hides under stage drain)
        float xg0a = 0.f, xg1a = 0.f, xg2a = 0.f, xg3a = 0.f;
        float xg0b = 0.f, xg1b = 0.f, xg2b = 0.f, xg3b = 0.f;
        if (ks == 0) {
            const float* xt = xpartT + (size_t)t * BB;
            xg0a = xt[(size_t)(0 * DH + jj) * NROWS + bq];
            xg1a = xt[(size_t)(1 * DH + jj) * NROWS + bq];
            xg2a = xt[(size_t)(2 * DH + jj) * NROWS + bq];
            xg3a = xt[(size_t)(3 * DH + jj) * NROWS + bq];
            xg0b = xt[(size_t)(0 * DH + jj) * NROWS + bq + 16];
            xg1b = xt[(size_t)(1 * DH + jj) * NROWS + bq + 16];
            xg2b = xt[(size_t)(2 * DH + jj) * NROWS + bq + 16];
            xg3b = xt[(size_t)(3 * DH + jj) * NROWS + bq + 16];
        }

        const float* hR = (t == 0) ? h0 : ((t & 1) ? hTA : hTB);   // r5 parity
        // ---- stage h: 8 coalesced uncached dwordx4/thread -> padded LDS tiles ----
        {
            f32x4 v[8];
#pragma unroll
            for (int q = 0; q < 8; ++q)
                asm volatile("global_load_dwordx4 %0, %1, off sc0 sc1"
                             : "=&v"(v[q]) : "v"(hR + (q * 512 + tid) * 4));
            asm volatile("s_waitcnt vmcnt(0)" ::: "memory");
            __builtin_amdgcn_sched_barrier(0);
#pragma unroll
            for (int q = 0; q < 8; ++q) {
                int f = q * 512 + tid;           // global float4 idx: b2*128 + ks2*8 + r2
                int b2 = f >> 7;
                int ks2 = (f & 127) >> 3;
                int r2 = f & 7;
                *(f32x4*)&h_lds[((b2 * 8 + r2) * 17 + ks2) * 4] = v[q];
            }
        }
        __syncthreads();

        // ---- partial dot: W regs x LDS h, 2 b-values, ks-slice of 32 cols ----
        float a0a = 0.f, a1a = 0.f, a2a = 0.f, a3a = 0.f;
        float a0b = 0.f, a1b = 0.f, a2b = 0.f, a3b = 0.f;
#pragma unroll
        for (int r = 0; r < 8; ++r) {
            f32x4 ha = *(const f32x4*)&h_lds[((bq * 8 + r) * 17 + ks) * 4];
            f32x4 hb = *(const f32x4*)&h_lds[(((bq + 16) * 8 + r) * 17 + ks) * 4];
            a0a += wreg[0][r][0] * ha[0] + wreg[0][r][1] * ha[1]
                 + wreg[0][r][2] * ha[2] + wreg[0][r][3] * ha[3];
            a1a += wreg[1][r][0] * ha[0] + wreg[1][r][1] * ha[1]
                 + wreg[1][r][2] * ha[2] + wreg[1][r][3] * ha[3];
            a2a += wreg[2][r][0] * ha[0] + wreg[2][r][1] * ha[1]
                 + wreg[2][r][2] * ha[2] + wreg[2][r][3] * ha[3];
            a3a += wreg[3][r][0] * ha[0] + wreg[3][r][1] * ha[1]
                 + wreg[3][r][2] * ha[2] + wreg[3][r][3] * ha[3];
            a0b += wreg[0][r][0] * hb[0] + wreg[0][r][1] * hb[1]
                 + wreg[0][r][2] * hb[2] + wreg[0][r][3] * hb[3];
            a1b += wreg[1][r][0] * hb[0] + wreg[1][r][1] * hb[1]
                 + wreg[1][r][2] * hb[2] + wreg[1][r][3] * hb[3];
            a2b += wreg[2][r][0] * hb[0] + wreg[2][r][1] * hb[1]
                 + wreg[2][r][2] * hb[2] + wreg[2][r][3] * hb[3];
            a3b += wreg[3][r][0] * hb[0] + wreg[3][r][1] * hb[1]
                 + wreg[3][r][2] * hb[2] + wreg[3][r][3] * hb[3];
        }
        // reduce over ks (lane bits 0..3)
#pragma unroll
        for (int d = 1; d <= 8; d <<= 1) {
            a0a += __shfl_xor(a0a, d); a1a += __shfl_xor(a1a, d);
            a2a += __shfl_xor(a2a, d); a3a += __shfl_xor(a3a, d);
            a0b += __shfl_xor(a0b, d); a1b += __shfl_xor(a1b, d);
            a2b += __shfl_xor(a2b, d); a3b += __shfl_xor(a3b, d);
        }

        if (ks == 0) {
            float* wb = (t & 1) ? hTB : hTA;          // r5 writer parity
#pragma unroll
            for (int bh = 0; bh < 2; ++bh) {
                int b = bh ? bq + 16 : bq;
                float gi = (bh ? a0b : a0a) + (bh ? xg0b : xg0a);
                float gf = (bh ? a1b : a1a) + (bh ? xg1b : xg1a);
                float gg = (bh ? a2b : a2a) + (bh ? xg2b : xg2a);
                float go = (bh ? a3b : a3a) + (bh ? xg3b : xg3a);
                float si = 1.f / (1.f + __expf(-gi));
                float sf = 1.f / (1.f + __expf(-gf));
                float tg = tanhf(gg);
                float so = 1.f / (1.f + __expf(-go));
                float cc = bh ? creg1 : creg0;
                cc = sf * cc + si * tg;
                float hn = so * tanhf(cc);
                if (bh) creg1 = cc; else creg0 = cc;

                coh_store(&wb[(size_t)b * DH + jj], hn);  // [b][j] layout
                int row = t * BB + b;
                Hall[(size_t)row * DH + jj] = hn;
                catbuf[(size_t)row * 1024 + jj] = f2bf(hn);
                if (t == TT - 1) {
                    hf[(size_t)b * DH + jj] = hn;
                    cf[(size_t)b * DH + jj] = cc;
                }
            }
        }

        // ---- device barrier: 8-leaf arrival tree (r11-proven) ----
        __syncthreads();   // drains vmcnt before s_barrier -> h stores done
        if (tid == 0) {
            asm volatile("s_waitcnt vmcnt(0)" ::: "memory");
            __hip_atomic_fetch_add(&cnt[t * 128 + (blockIdx.x & (NLEAF - 1)) * 16], 1,
                                   __ATOMIC_RELAXED, __HIP_MEMORY_SCOPE_AGENT);
        }
        if (tid < NLEAF) {
            while (__hip_atomic_load(&cnt[t * 128 + tid * 16], __ATOMIC_RELAXED,
                                     __HIP_MEMORY_SCOPE_AGENT) < LEAF_TARGET) {
                __builtin_amdgcn_s_sleep(1);
            }
        }
        __syncthreads();
    }
}

// ---------------- attention: scores -> softmax -> wctx (per (b, 4 t's)) ----------------
__global__ __launch_bounds__(256)
void k_attn(const float* __restrict__ Hall, const float* __restrict__ ctx,
            unsigned short* __restrict__ catbuf) {
    __shared__ float h4[4][DH];
    __shared__ float p_lds[4][SS];
    __shared__ float l_lds[4];

    const int tid = threadIdx.x;
    const int b = blockIdx.x & 31;
    const int tg = blockIdx.x >> 5;

    for (int i = tid; i < 4 * DH / 4; i += 256) {
        int e = i * 4;
        int ti = e >> 9, k = e & 511;
        float4 v = *(const float4*)(Hall + ((size_t)((tg * 4 + ti) * BB + b)) * DH + k);
        h4[ti][k + 0] = v.x; h4[ti][k + 1] = v.y; h4[ti][k + 2] = v.z; h4[ti][k + 3] = v.w;
    }
    __syncthreads();

    {
        int s = tid;
        float acc[4] = {0.f, 0.f, 0.f, 0.f};
        const float4* cp = (const float4*)(ctx + ((size_t)b * SS + s) * DH);
        for (int kc = 0; kc < DH / 4; ++kc) {
            float4 cv = cp[kc];
#pragma unroll
            for (int i = 0; i < 4; ++i) {
                float4 hv = *(const float4*)&h4[i][kc * 4];
                acc[i] += cv.x * hv.x + cv.y * hv.y + cv.z * hv.z + cv.w * hv.w;
            }
        }
#pragma unroll
        for (int i = 0; i < 4; ++i) p_lds[i][s] = acc[i];
    }
    __syncthreads();

    {
        int w = tid >> 6, l = tid & 63;
        float v0 = p_lds[w][l], v1 = p_lds[w][l + 64];
        float v2 = p_lds[w][l + 128], v3 = p_lds[w][l + 192];
        float mx = fmaxf(fmaxf(v0, v1), fmaxf(v2, v3));
        for (int d = 1; d < 64; d <<= 1) mx = fmaxf(mx, __shfl_xor(mx, d));
        float e0 = __expf(v0 - mx), e1 = __expf(v1 - mx);
        float e2 = __expf(v2 - mx), e3 = __expf(v3 - mx);
        float ssum = e0 + e1 + e2 + e3;
        for (int d = 1; d < 64; d <<= 1) ssum += __shfl_xor(ssum, d);
        p_lds[w][l] = e0; p_lds[w][l + 64] = e1;
        p_lds[w][l + 128] = e2; p_lds[w][l + 192] = e3;
        if (l == 0) l_lds[w] = ssum;
    }
    __syncthreads();

    {
        int d0 = tid * 2;
        float accx[4], accy[4];
#pragma unroll
        for (int i = 0; i < 4; ++i) { accx[i] = 0.f; accy[i] = 0.f; }
        const float* cb = ctx + (size_t)b * SS * DH + d0;
        for (int s = 0; s < SS; ++s) {
            float2 cv = *(const float2*)(cb + (size_t)s * DH);
#pragma unroll
            for (int i = 0; i < 4; ++i) {
                float p = p_lds[i][s];
                accx[i] += p * cv.x;
                accy[i] += p * cv.y;
            }
        }
#pragma unroll
        for (int i = 0; i < 4; ++i) {
            float inv = 1.f / l_lds[i];
            int row = (tg * 4 + i) * BB + b;
            unsigned pack = (unsigned)f2bf(accx[i] * inv) | ((unsigned)f2bf(accy[i] * inv) << 16);
            *(unsigned*)&catbuf[(size_t)row * 1024 + DH + d0] = pack;
        }
    }
}

// ---------------- fused lse + subtract (one block per row) ----------------
__global__ __launch_bounds__(256)
void k_lsesub(float* __restrict__ logp, const float* __restrict__ pm,
              const float* __restrict__ ps, int nt) {
    __shared__ float sL;
    const int row = blockIdx.x;
    const int tid = threadIdx.x;
    if (tid < 64) {
        const float* pmr = pm + (size_t)row * nt;
        const float* psr = ps + (size_t)row * nt;
        float m = -1e30f;
        for (int i = tid; i < nt; i += 64) m = fmaxf(m, pmr[i]);
        for (int d = 1; d < 64; d <<= 1) m = fmaxf(m, __shfl_xor(m, d));
        float s = 0.f;
        for (int i = tid; i < nt; i += 64) s += psr[i] * __expf(pmr[i] - m);
        for (int d = 1; d < 64; d <<= 1) s += __shfl_xor(s, d);
        if (tid == 0) sL = m + logf(s);
    }
    __syncthreads();
    float L = sL;
    float4* p = (float4*)(logp + (size_t)row * VV);
    for (int i = tid; i < VV / 4; i += 256) {
        float4 v = p[i];
        v.x -= L; v.y -= L; v.z -= L; v.w -= L;
        p[i] = v;
    }
}

// ---------------- host launch ----------------
extern "C" void kernel_launch(void* const* d_in, const int* in_sizes, int n_in,
                              void* d_out, int out_size, void* d_ws, size_t ws_size,
                              hipStream_t stream) {
    const int*   xseq  = (const int*)d_in[0];
    const float* h0    = (const float*)d_in[1];
    const float* c0    = (const float*)d_in[2];
    const float* ctx   = (const float*)d_in[3];
    const float* emb   = (const float*)d_in[4];
    const float* Wih   = (const float*)d_in[5];
    const float* Whh   = (const float*)d_in[6];
    const float* bih   = (const float*)d_in[7];
    const float* bhh   = (const float*)d_in[8];
    const float* Wattn = (const float*)d_in[9];
    const float* Wout  = (const float*)d_in[10];
    const float* bout  = (const float*)d_in[11];
    float* out = (float*)d_out;

    char* wptr = (char*)d_ws;
    auto carve = [&](size_t bytes) {
        char* p = wptr;
        wptr += (bytes + 255) & ~(size_t)255;
        return p;
    };
    float*          xpartT  = (float*)carve((size_t)NROWS * G4 * 4);
    float*          Hall    = (float*)carve((size_t)NROWS * DH * 4);
    unsigned short* catbf   = (unsigned short*)carve((size_t)NROWS * 1024 * 2);
    unsigned short* outsbf  = (unsigned short*)carve((size_t)NROWS * DH * 2);
    float*          ef32    = (float*)carve((size_t)NROWS * DH * 4);
    unsigned short* Wattnbf = (unsigned short*)carve((size_t)DH * 1024 * 2);
    unsigned short* Woutbf  = (unsigned short*)carve((size_t)VV * DH * 2);
    float*          hTA     = (float*)carve((size_t)BB * DH * 4);
    float*          hTB     = (float*)carve((size_t)BB * DH * 4);
    int*            cnt     = (int*)carve((size_t)TT * 128 * 4);
    float*          pm      = (float*)carve((size_t)NROWS * 250 * 4);
    float*          ps      = (float*)carve((size_t)NROWS * 250 * 4);

    // prep
    k_convert_bf16<<<256, 256, 0, stream>>>(Wattn, Wattnbf, DH * 1024 / 4);
    k_convert_bf16<<<2048, 256, 0, stream>>>(Wout, Woutbf, VV * DH / 4);
    k_gather_embed32<<<NROWS, 128, 0, stream>>>(xseq, emb, ef32);
    k_scan_init<<<32, 256, 0, stream>>>(cnt);

    // x_part^T = (e @ W_ih^T + b_ih + b_hh)^T   -- full fp32, transposed write
    k_sgemm_xpart<<<dim3(16, 16), 256, 0, stream>>>(
        ef32, Wih, bih, bhh, xpartT, NROWS, G4, DH);

    // sequential LSTM scan (cooperative; register-W, leaf-tree barrier)
    {
        const float* a0 = xpartT; const float* a1 = Whh;
        const float* a2 = h0;     const float* a3 = c0;
        float* a4 = hTA; float* a5 = hTB; float* a6 = Hall;
        unsigned short* a7 = catbf;
        float* a8 = out + (size_t)NROWS * VV;           // hf
        float* a9 = a8 + BB * DH;                       // cf
        int* a10 = cnt;
        void* args[] = {&a0, &a1, &a2, &a3, &a4, &a5, &a6, &a7, &a8, &a9, &a10};
        hipLaunchCooperativeKernel((const void*)k_lstm_scan, dim3(NBLK_SCAN), dim3(512),
                                   args, 0, stream);
    }

    // attention (parallel over all t,b)
    k_attn<<<512, 256, 0, stream>>>(Hall, ctx, catbf);

    // outs = tanh(cat @ W_attn^T)  -> bf16
    k_mfma_gemm<1><<<dim3(4, 16), 256, 0, stream>>>(
        catbf, Wattnbf, NROWS, DH, 1024, nullptr, nullptr, outsbf, nullptr, nullptr);

    // logits = outs @ W_out^T + b_out -> d_out (fp32) + softmax partials
    k_mfma_gemm<2><<<dim3(250, 16), 256, 0, stream>>>(
        outsbf, Woutbf, NROWS, VV, DH, bout, out, nullptr, pm, ps);

    // fused lse + in-place logp
    k_lsesub<<<NROWS, 256, 0, stream>>>(out, pm, ps, 250);
}

// Round 14
// 883.730 us; speedup vs baseline: 1.6915x; 1.1114x over previous
//
#include <hip/hip_runtime.h>
#include <hip/hip_cooperative_groups.h>
#include <cstdint>
#include <cstddef>

namespace cg = cooperative_groups;

#define TT 64
#define BB 32
#define SS 256
#define DH 512
#define VV 32000
#define NROWS 2048   // T*B
#define G4 2048      // 4*DH
#define NBLK_SCAN 256
#define NLEAF 32
#define LEAF_TARGET (NBLK_SCAN / NLEAF)   // 8 arrivals per leaf

typedef __attribute__((ext_vector_type(8))) short short8;
typedef __attribute__((ext_vector_type(4))) float f32x4;

__device__ __forceinline__ unsigned short f2bf(float x) {
    unsigned u = __float_as_uint(x);
    u += 0x7FFFu + ((u >> 16) & 1u);   // RNE
    return (unsigned short)(u >> 16);
}
__device__ __forceinline__ float bf2f(unsigned short u) {
    return __uint_as_float((unsigned)u << 16);
}

__device__ __forceinline__ void gload_lds16(const void* g, void* l) {
    __builtin_amdgcn_global_load_lds(
        (const __attribute__((address_space(1))) unsigned int*)g,
        (__attribute__((address_space(3))) unsigned int*)l, 16, 0, 0);
}

// coherent (agent-scope) dword store -- proven cross-XCD exchange primitive
__device__ __forceinline__ void coh_store(float* p, float v) {
    __hip_atomic_store(p, v, __ATOMIC_RELAXED, __HIP_MEMORY_SCOPE_AGENT);
}

// ---------------- prep kernels ----------------
__global__ void k_convert_bf16(const float* __restrict__ src,
                               unsigned short* __restrict__ dst, int n4) {
    int i = blockIdx.x * blockDim.x + threadIdx.x;
    int stride = gridDim.x * blockDim.x;
    for (; i < n4; i += stride) {
        float4 v = ((const float4*)src)[i];
        ushort4 o;
        o.x = f2bf(v.x); o.y = f2bf(v.y); o.z = f2bf(v.z); o.w = f2bf(v.w);
        ((ushort4*)dst)[i] = o;
    }
}

// fp32 -> hi/lo bf16 planes
__global__ void k_convert_hl(const float* __restrict__ src,
                             unsigned short* __restrict__ hi,
                             unsigned short* __restrict__ lo, int n4) {
    int i = blockIdx.x * blockDim.x + threadIdx.x;
    int stride = gridDim.x * blockDim.x;
    for (; i < n4; i += stride) {
        float4 v = ((const float4*)src)[i];
        ushort4 oh, ol;
        float f[4] = {v.x, v.y, v.z, v.w};
        unsigned short h[4], l[4];
#pragma unroll
        for (int e = 0; e < 4; ++e) {
            h[e] = f2bf(f[e]);
            l[e] = f2bf(f[e] - bf2f(h[e]));
        }
        oh.x = h[0]; oh.y = h[1]; oh.z = h[2]; oh.w = h[3];
        ol.x = l[0]; ol.y = l[1]; ol.z = l[2]; ol.w = l[3];
        ((ushort4*)hi)[i] = oh;
        ((ushort4*)lo)[i] = ol;
    }
}

// gather embedding rows + split into hi/lo bf16 planes
__global__ void k_gather_embed_hl(const int* __restrict__ xseq,
                                  const float* __restrict__ emb,
                                  unsigned short* __restrict__ ehi,
                                  unsigned short* __restrict__ elo) {
    int r = blockIdx.x;
    int tok = xseq[r];
    const float4* s = (const float4*)(emb + (size_t)tok * DH);
    ushort4* dh = (ushort4*)(ehi + (size_t)r * DH);
    ushort4* dl = (ushort4*)(elo + (size_t)r * DH);
    for (int i = threadIdx.x; i < DH / 4; i += blockDim.x) {
        float4 v = s[i];
        float f[4] = {v.x, v.y, v.z, v.w};
        unsigned short h[4], l[4];
#pragma unroll
        for (int e = 0; e < 4; ++e) {
            h[e] = f2bf(f[e]);
            l[e] = f2bf(f[e] - bf2f(h[e]));
        }
        dh[i] = make_ushort4(h[0], h[1], h[2], h[3]);
        dl[i] = make_ushort4(l[0], l[1], l[2], l[3]);
    }
}

// zero barrier counters
__global__ void k_scan_init(int* __restrict__ cnt) {
    int i = blockIdx.x * blockDim.x + threadIdx.x;
    if (i < TT * NLEAF * 16) cnt[i] = 0;
}

// ---- hi/lo bf16 MFMA GEMM for xpart: Ct[N,M] = (A @ B^T + b1 + b2)^T ----
// A,B given as hi/lo bf16 planes; acc += Ahi*Bhi + Ahi*Blo + Alo*Bhi (~fp32).
// Skeleton identical to the proven k_mfma_gemm; transposed float4 epilogue.
__global__ __launch_bounds__(256)
void k_mfma_xpart(const unsigned short* __restrict__ Ahi, const unsigned short* __restrict__ Alo,
                  const unsigned short* __restrict__ Bhi, const unsigned short* __restrict__ Blo,
                  int M, int N, int K,
                  const float* __restrict__ b1, const float* __restrict__ b2,
                  float* __restrict__ Ct) {
    __shared__ unsigned short Ah_s[128 * 64];
    __shared__ unsigned short Al_s[128 * 64];
    __shared__ unsigned short Bh_s[128 * 64];
    __shared__ unsigned short Bl_s[128 * 64];

    const int tid = threadIdx.x;
    const int lane = tid & 63;
    const int wid = tid >> 6;
    const int wm = wid >> 1, wn = wid & 1;
    const int mrow0 = blockIdx.y * 128;
    const int ncol0 = blockIdx.x * 128;
    const int lr = lane & 15;
    const int lk = (lane >> 4) * 8;
    const int rw = (lane >> 4) * 4;

    f32x4 acc[4][4] = {};

    for (int kt = 0; kt < K; kt += 64) {
#pragma unroll
        for (int it = 0; it < 4; ++it) {
            int chunk = it * 256 + tid;
            int r = chunk >> 3;
            int c = (chunk & 7) * 8;
            size_t goA = (size_t)(mrow0 + r) * K + kt + c;
            size_t goB = (size_t)(ncol0 + r) * K + kt + c;
            gload_lds16(Ahi + goA, (void*)(Ah_s + chunk * 8));
            gload_lds16(Alo + goA, (void*)(Al_s + chunk * 8));
            gload_lds16(Bhi + goB, (void*)(Bh_s + chunk * 8));
            gload_lds16(Blo + goB, (void*)(Bl_s + chunk * 8));
        }
        __syncthreads();
#pragma unroll
        for (int kk = 0; kk < 2; ++kk) {
            short8 ah[4], al[4], bh[4], bl[4];
#pragma unroll
            for (int i = 0; i < 4; ++i) {
                int offA = (wm * 64 + i * 16 + lr) * 64 + kk * 32 + lk;
                int offB = (wn * 64 + i * 16 + lr) * 64 + kk * 32 + lk;
                ah[i] = *(const short8*)&Ah_s[offA];
                al[i] = *(const short8*)&Al_s[offA];
                bh[i] = *(const short8*)&Bh_s[offB];
                bl[i] = *(const short8*)&Bl_s[offB];
            }
#pragma unroll
            for (int mi = 0; mi < 4; ++mi)
#pragma unroll
                for (int ni = 0; ni < 4; ++ni) {
                    acc[mi][ni] = __builtin_amdgcn_mfma_f32_16x16x32_bf16(
                        ah[mi], bh[ni], acc[mi][ni], 0, 0, 0);
                    acc[mi][ni] = __builtin_amdgcn_mfma_f32_16x16x32_bf16(
                        ah[mi], bl[ni], acc[mi][ni], 0, 0, 0);
                    acc[mi][ni] = __builtin_amdgcn_mfma_f32_16x16x32_bf16(
                        al[mi], bh[ni], acc[mi][ni], 0, 0, 0);
                }
        }
        __syncthreads();
    }

    // transposed epilogue: Ct[col][row], rows r=0..3 contiguous -> float4 store
#pragma unroll
    for (int ni = 0; ni < 4; ++ni) {
        int col = ncol0 + wn * 64 + ni * 16 + lr;
        float bs = b1[col] + b2[col];
#pragma unroll
        for (int mi = 0; mi < 4; ++mi) {
            int grow0 = mrow0 + wm * 64 + mi * 16 + rw;
            float4 o;
            o.x = acc[mi][ni][0] + bs;
            o.y = acc[mi][ni][1] + bs;
            o.z = acc[mi][ni][2] + bs;
            o.w = acc[mi][ni][3] + bs;
            *(float4*)&Ct[(size_t)col * M + grow0] = o;
        }
    }
}

// ---------------- MFMA GEMM: C[M,N] = A[M,K] @ B[N,K]^T (+epilogue) ----------------
template <int EPI>
__global__ __launch_bounds__(256)
void k_mfma_gemm(const unsigned short* __restrict__ A,
                 const unsigned short* __restrict__ B,
                 int M, int N, int K,
                 const float* __restrict__ bias,
                 float* __restrict__ Cf,
                 unsigned short* __restrict__ Cbf,
                 float* __restrict__ pm, float* __restrict__ ps) {
    __shared__ unsigned short A_s[128 * 64];
    __shared__ unsigned short B_s[128 * 64];
    __shared__ float part_m[2][128];
    __shared__ float part_s[2][128];

    const int tid = threadIdx.x;
    const int lane = tid & 63;
    const int wid = tid >> 6;
    const int wm = wid >> 1, wn = wid & 1;
    const int mrow0 = blockIdx.y * 128;
    const int ncol0 = blockIdx.x * 128;
    const int lr = lane & 15;
    const int lk = (lane >> 4) * 8;
    const int rw = (lane >> 4) * 4;

    f32x4 acc[4][4] = {};

    for (int kt = 0; kt < K; kt += 64) {
#pragma unroll
        for (int it = 0; it < 4; ++it) {
            int chunk = it * 256 + tid;
            int r = chunk >> 3;
            int c = (chunk & 7) * 8;
            gload_lds16(A + (size_t)(mrow0 + r) * K + kt + c, (void*)(A_s + chunk * 8));
            gload_lds16(B + (size_t)(ncol0 + r) * K + kt + c, (void*)(B_s + chunk * 8));
        }
        __syncthreads();
#pragma unroll
        for (int kk = 0; kk < 2; ++kk) {
            short8 afr[4], bfr[4];
#pragma unroll
            for (int i = 0; i < 4; ++i) {
                afr[i] = *(const short8*)&A_s[(wm * 64 + i * 16 + lr) * 64 + kk * 32 + lk];
                bfr[i] = *(const short8*)&B_s[(wn * 64 + i * 16 + lr) * 64 + kk * 32 + lk];
            }
#pragma unroll
            for (int mi = 0; mi < 4; ++mi)
#pragma unroll
                for (int ni = 0; ni < 4; ++ni)
                    acc[mi][ni] = __builtin_amdgcn_mfma_f32_16x16x32_bf16(
                        afr[mi], bfr[ni], acc[mi][ni], 0, 0, 0);
        }
        __syncthreads();
    }

    if constexpr (EPI == 1) {
#pragma unroll
        for (int ni = 0; ni < 4; ++ni) {
            int col = ncol0 + wn * 64 + ni * 16 + lr;
#pragma unroll
            for (int mi = 0; mi < 4; ++mi)
#pragma unroll
                for (int r = 0; r < 4; ++r) {
                    int grow = mrow0 + wm * 64 + mi * 16 + rw + r;
                    Cbf[(size_t)grow * N + col] = f2bf(tanhf(acc[mi][ni][r]));
                }
        }
    } else {
        float bv[4];
#pragma unroll
        for (int ni = 0; ni < 4; ++ni) bv[ni] = bias[ncol0 + wn * 64 + ni * 16 + lr];
#pragma unroll
        for (int mi = 0; mi < 4; ++mi) {
#pragma unroll
            for (int r = 0; r < 4; ++r) {
                int grow = mrow0 + wm * 64 + mi * 16 + rw + r;
                float v[4];
                float mx = -1e30f;
#pragma unroll
                for (int ni = 0; ni < 4; ++ni) {
                    v[ni] = acc[mi][ni][r] + bv[ni];
                    int col = ncol0 + wn * 64 + ni * 16 + lr;
                    Cf[(size_t)grow * N + col] = v[ni];
                    mx = fmaxf(mx, v[ni]);
                }
#pragma unroll
                for (int d = 1; d <= 8; d <<= 1) mx = fmaxf(mx, __shfl_xor(mx, d));
                float ssum = 0.f;
#pragma unroll
                for (int ni = 0; ni < 4; ++ni) ssum += __expf(v[ni] - mx);
#pragma unroll
                for (int d = 1; d <= 8; d <<= 1) ssum += __shfl_xor(ssum, d);
                if (lr == 0) {
                    int lrow = wm * 64 + mi * 16 + rw + r;
                    part_m[wn][lrow] = mx;
                    part_s[wn][lrow] = ssum;
                }
            }
        }
        __syncthreads();
        if (tid < 128) {
            float m0v = part_m[0][tid], m1v = part_m[1][tid];
            float mm = fmaxf(m0v, m1v);
            float ssum = part_s[0][tid] * __expf(m0v - mm) + part_s[1][tid] * __expf(m1v - mm);
            int grow = mrow0 + tid;
            pm[(size_t)grow * gridDim.x + blockIdx.x] = mm;
            ps[(size_t)grow * gridDim.x + blockIdx.x] = ssum;
        }
    }
}

// ---------------- LSTM scan: register-W ks-split dot, 512 threads (r13-proven) ----
__global__ __launch_bounds__(512, 2)
void k_lstm_scan(const float* __restrict__ xpartT, const float* __restrict__ Whh,
                 const float* __restrict__ h0, const float* __restrict__ c0,
                 float* __restrict__ hTA, float* __restrict__ hTB,
                 float* __restrict__ Hall, unsigned short* __restrict__ catbuf,
                 float* __restrict__ hf, float* __restrict__ cf,
                 int* __restrict__ cnt) {
    __shared__ __align__(16) float h_lds[BB * 8 * 17 * 4];   // 69.6 KB

    const int tid = threadIdx.x;
    const int jl = tid >> 8;             // 0..1
    const int bq = (tid >> 4) & 15;      // handles b = bq, bq+16
    const int ks = tid & 15;             // k-slice: cols ks*32 .. ks*32+31
    const int jj = blockIdx.x * 2 + jl;

    // --- prologue: this thread's W slice into registers (4 gates x 32 cols) ---
    f32x4 wreg[4][8];
#pragma unroll
    for (int g = 0; g < 4; ++g) {
        const float* wp = Whh + (size_t)(g * DH + jj) * DH + ks * 32;
#pragma unroll
        for (int r = 0; r < 8; ++r)
            wreg[g][r] = *(const f32x4*)(wp + r * 4);
    }

    float creg0 = c0[(size_t)bq * DH + jj];          // used only by ks==0
    float creg1 = c0[(size_t)(bq + 16) * DH + jj];

    for (int t = 0; t < TT; ++t) {
        // xpart bias prefetch (cached; latency hides under stage drain)
        float xg0a = 0.f, xg1a = 0.f, xg2a = 0.f, xg3a = 0.f;
        float xg0b = 0.f, xg1b = 0.f, xg2b = 0.f, xg3b = 0.f;
        if (ks == 0) {
            const float* xt = xpartT + (size_t)t * BB;
            xg0a = xt[(size_t)(0 * DH + jj) * NROWS + bq];
            xg1a = xt[(size_t)(1 * DH + jj) * NROWS + bq];
            xg2a = xt[(size_t)(2 * DH + jj) * NROWS + bq];
            xg3a = xt[(size_t)(3 * DH + jj) * NROWS + bq];
            xg0b = xt[(size_t)(0 * DH + jj) * NROWS + bq + 16];
            xg1b = xt[(size_t)(1 * DH + jj) * NROWS + bq + 16];
            xg2b = xt[(size_t)(2 * DH + jj) * NROWS + bq + 16];
            xg3b = xt[(size_t)(3 * DH + jj) * NROWS + bq + 16];
        }

        const float* hR = (t == 0) ? h0 : ((t & 1) ? hTA : hTB);   // r5 parity
        // ---- stage h: 8 coalesced uncached dwordx4/thread -> padded LDS tiles ----
        {
            f32x4 v[8];
#pragma unroll
            for (int q = 0; q < 8; ++q)
                asm volatile("global_load_dwordx4 %0, %1, off sc0 sc1"
                             : "=&v"(v[q]) : "v"(hR + (q * 512 + tid) * 4));
            asm volatile("s_waitcnt vmcnt(0)" ::: "memory");
            __builtin_amdgcn_sched_barrier(0);
#pragma unroll
            for (int q = 0; q < 8; ++q) {
                int f = q * 512 + tid;           // global float4 idx: b2*128 + ks2*8 + r2
                int b2 = f >> 7;
                int ks2 = (f & 127) >> 3;
                int r2 = f & 7;
                *(f32x4*)&h_lds[((b2 * 8 + r2) * 17 + ks2) * 4] = v[q];
            }
        }
        __syncthreads();

        // ---- partial dot: W regs x LDS h, 2 b-values, ks-slice of 32 cols ----
        float a0a = 0.f, a1a = 0.f, a2a = 0.f, a3a = 0.f;
        float a0b = 0.f, a1b = 0.f, a2b = 0.f, a3b = 0.f;
#pragma unroll
        for (int r = 0; r < 8; ++r) {
            f32x4 ha = *(const f32x4*)&h_lds[((bq * 8 + r) * 17 + ks) * 4];
            f32x4 hb = *(const f32x4*)&h_lds[(((bq + 16) * 8 + r) * 17 + ks) * 4];
            a0a += wreg[0][r][0] * ha[0] + wreg[0][r][1] * ha[1]
                 + wreg[0][r][2] * ha[2] + wreg[0][r][3] * ha[3];
            a1a += wreg[1][r][0] * ha[0] + wreg[1][r][1] * ha[1]
                 + wreg[1][r][2] * ha[2] + wreg[1][r][3] * ha[3];
            a2a += wreg[2][r][0] * ha[0] + wreg[2][r][1] * ha[1]
                 + wreg[2][r][2] * ha[2] + wreg[2][r][3] * ha[3];
            a3a += wreg[3][r][0] * ha[0] + wreg[3][r][1] * ha[1]
                 + wreg[3][r][2] * ha[2] + wreg[3][r][3] * ha[3];
            a0b += wreg[0][r][0] * hb[0] + wreg[0][r][1] * hb[1]
                 + wreg[0][r][2] * hb[2] + wreg[0][r][3] * hb[3];
            a1b += wreg[1][r][0] * hb[0] + wreg[1][r][1] * hb[1]
                 + wreg[1][r][2] * hb[2] + wreg[1][r][3] * hb[3];
            a2b += wreg[2][r][0] * hb[0] + wreg[2][r][1] * hb[1]
                 + wreg[2][r][2] * hb[2] + wreg[2][r][3] * hb[3];
            a3b += wreg[3][r][0] * hb[0] + wreg[3][r][1] * hb[1]
                 + wreg[3][r][2] * hb[2] + wreg[3][r][3] * hb[3];
        }
        // reduce over ks (lane bits 0..3)
#pragma unroll
        for (int d = 1; d <= 8; d <<= 1) {
            a0a += __shfl_xor(a0a, d); a1a += __shfl_xor(a1a, d);
            a2a += __shfl_xor(a2a, d); a3a += __shfl_xor(a3a, d);
            a0b += __shfl_xor(a0b, d); a1b += __shfl_xor(a1b, d);
            a2b += __shfl_xor(a2b, d); a3b += __shfl_xor(a3b, d);
        }

        if (ks == 0) {
            float* wb = (t & 1) ? hTB : hTA;          // r5 writer parity
#pragma unroll
            for (int bh = 0; bh < 2; ++bh) {
                int b = bh ? bq + 16 : bq;
                float gi = (bh ? a0b : a0a) + (bh ? xg0b : xg0a);
                float gf = (bh ? a1b : a1a) + (bh ? xg1b : xg1a);
                float gg = (bh ? a2b : a2a) + (bh ? xg2b : xg2a);
                float go = (bh ? a3b : a3a) + (bh ? xg3b : xg3a);
                float si = 1.f / (1.f + __expf(-gi));
                float sf = 1.f / (1.f + __expf(-gf));
                float tg = tanhf(gg);
                float so = 1.f / (1.f + __expf(-go));
                float cc = bh ? creg1 : creg0;
                cc = sf * cc + si * tg;
                float hn = so * tanhf(cc);
                if (bh) creg1 = cc; else creg0 = cc;

                coh_store(&wb[(size_t)b * DH + jj], hn);  // [b][j] layout
                int row = t * BB + b;
                Hall[(size_t)row * DH + jj] = hn;
                catbuf[(size_t)row * 1024 + jj] = f2bf(hn);
                if (t == TT - 1) {
                    hf[(size_t)b * DH + jj] = hn;
                    cf[(size_t)b * DH + jj] = cc;
                }
            }
        }

        // ---- device barrier: 32-leaf arrival tree ----
        __syncthreads();   // drains vmcnt before s_barrier -> h stores done
        if (tid == 0) {
            asm volatile("s_waitcnt vmcnt(0)" ::: "memory");
            __hip_atomic_fetch_add(&cnt[t * (NLEAF * 16) + (blockIdx.x & (NLEAF - 1)) * 16], 1,
                                   __ATOMIC_RELAXED, __HIP_MEMORY_SCOPE_AGENT);
        }
        if (tid < NLEAF) {
            while (__hip_atomic_load(&cnt[t * (NLEAF * 16) + tid * 16], __ATOMIC_RELAXED,
                                     __HIP_MEMORY_SCOPE_AGENT) < LEAF_TARGET) {
                __builtin_amdgcn_s_sleep(1);
            }
        }
        __syncthreads();
    }
}

// ---------------- attention: scores -> softmax -> wctx (per (b, 4 t's)) ----------------
__global__ __launch_bounds__(256)
void k_attn(const float* __restrict__ Hall, const float* __restrict__ ctx,
            unsigned short* __restrict__ catbuf) {
    __shared__ float h4[4][DH];
    __shared__ float p_lds[4][SS];
    __shared__ float l_lds[4];

    const int tid = threadIdx.x;
    const int b = blockIdx.x & 31;
    const int tg = blockIdx.x >> 5;

    for (int i = tid; i < 4 * DH / 4; i += 256) {
        int e = i * 4;
        int ti = e >> 9, k = e & 511;
        float4 v = *(const float4*)(Hall + ((size_t)((tg * 4 + ti) * BB + b)) * DH + k);
        h4[ti][k + 0] = v.x; h4[ti][k + 1] = v.y; h4[ti][k + 2] = v.z; h4[ti][k + 3] = v.w;
    }
    __syncthreads();

    {
        int s = tid;
        float acc[4] = {0.f, 0.f, 0.f, 0.f};
        const float4* cp = (const float4*)(ctx + ((size_t)b * SS + s) * DH);
        for (int kc = 0; kc < DH / 4; ++kc) {
            float4 cv = cp[kc];
#pragma unroll
            for (int i = 0; i < 4; ++i) {
                float4 hv = *(const float4*)&h4[i][kc * 4];
                acc[i] += cv.x * hv.x + cv.y * hv.y + cv.z * hv.z + cv.w * hv.w;
            }
        }
#pragma unroll
        for (int i = 0; i < 4; ++i) p_lds[i][s] = acc[i];
    }
    __syncthreads();

    {
        int w = tid >> 6, l = tid & 63;
        float v0 = p_lds[w][l], v1 = p_lds[w][l + 64];
        float v2 = p_lds[w][l + 128], v3 = p_lds[w][l + 192];
        float mx = fmaxf(fmaxf(v0, v1), fmaxf(v2, v3));
        for (int d = 1; d < 64; d <<= 1) mx = fmaxf(mx, __shfl_xor(mx, d));
        float e0 = __expf(v0 - mx), e1 = __expf(v1 - mx);
        float e2 = __expf(v2 - mx), e3 = __expf(v3 - mx);
        float ssum = e0 + e1 + e2 + e3;
        for (int d = 1; d < 64; d <<= 1) ssum += __shfl_xor(ssum, d);
        p_lds[w][l] = e0; p_lds[w][l + 64] = e1;
        p_lds[w][l + 128] = e2; p_lds[w][l + 192] = e3;
        if (l == 0) l_lds[w] = ssum;
    }
    __syncthreads();

    {
        int d0 = tid * 2;
        float accx[4], accy[4];
#pragma unroll
        for (int i = 0; i < 4; ++i) { accx[i] = 0.f; accy[i] = 0.f; }
        const float* cb = ctx + (size_t)b * SS * DH + d0;
        for (int s = 0; s < SS; ++s) {
            float2 cv = *(const float2*)(cb + (size_t)s * DH);
#pragma unroll
            for (int i = 0; i < 4; ++i) {
                float p = p_lds[i][s];
                accx[i] += p * cv.x;
                accy[i] += p * cv.y;
            }
        }
#pragma unroll
        for (int i = 0; i < 4; ++i) {
            float inv = 1.f / l_lds[i];
            int row = (tg * 4 + i) * BB + b;
            unsigned pack = (unsigned)f2bf(accx[i] * inv) | ((unsigned)f2bf(accy[i] * inv) << 16);
            *(unsigned*)&catbuf[(size_t)row * 1024 + DH + d0] = pack;
        }
    }
}

// ---------------- fused lse + subtract (one block per row) ----------------
__global__ __launch_bounds__(256)
void k_lsesub(float* __restrict__ logp, const float* __restrict__ pm,
              const float* __restrict__ ps, int nt) {
    __shared__ float sL;
    const int row = blockIdx.x;
    const int tid = threadIdx.x;
    if (tid < 64) {
        const float* pmr = pm + (size_t)row * nt;
        const float* psr = ps + (size_t)row * nt;
        float m = -1e30f;
        for (int i = tid; i < nt; i += 64) m = fmaxf(m, pmr[i]);
        for (int d = 1; d < 64; d <<= 1) m = fmaxf(m, __shfl_xor(m, d));
        float s = 0.f;
        for (int i = tid; i < nt; i += 64) s += psr[i] * __expf(pmr[i] - m);
        for (int d = 1; d < 64; d <<= 1) s += __shfl_xor(s, d);
        if (tid == 0) sL = m + logf(s);
    }
    __syncthreads();
    float L = sL;
    float4* p = (float4*)(logp + (size_t)row * VV);
    for (int i = tid; i < VV / 4; i += 256) {
        float4 v = p[i];
        v.x -= L; v.y -= L; v.z -= L; v.w -= L;
        p[i] = v;
    }
}

// ---------------- host launch ----------------
extern "C" void kernel_launch(void* const* d_in, const int* in_sizes, int n_in,
                              void* d_out, int out_size, void* d_ws, size_t ws_size,
                              hipStream_t stream) {
    const int*   xseq  = (const int*)d_in[0];
    const float* h0    = (const float*)d_in[1];
    const float* c0    = (const float*)d_in[2];
    const float* ctx   = (const float*)d_in[3];
    const float* emb   = (const float*)d_in[4];
    const float* Wih   = (const float*)d_in[5];
    const float* Whh   = (const float*)d_in[6];
    const float* bih   = (const float*)d_in[7];
    const float* bhh   = (const float*)d_in[8];
    const float* Wattn = (const float*)d_in[9];
    const float* Wout  = (const float*)d_in[10];
    const float* bout  = (const float*)d_in[11];
    float* out = (float*)d_out;

    char* wptr = (char*)d_ws;
    auto carve = [&](size_t bytes) {
        char* p = wptr;
        wptr += (bytes + 255) & ~(size_t)255;
        return p;
    };
    float*          xpartT  = (float*)carve((size_t)NROWS * G4 * 4);
    float*          Hall    = (float*)carve((size_t)NROWS * DH * 4);
    unsigned short* catbf   = (unsigned short*)carve((size_t)NROWS * 1024 * 2);
    unsigned short* outsbf  = (unsigned short*)carve((size_t)NROWS * DH * 2);
    unsigned short* ehi     = (unsigned short*)carve((size_t)NROWS * DH * 2);
    unsigned short* elo     = (unsigned short*)carve((size_t)NROWS * DH * 2);
    unsigned short* Wihhi   = (unsigned short*)carve((size_t)G4 * DH * 2);
    unsigned short* Wihlo   = (unsigned short*)carve((size_t)G4 * DH * 2);
    unsigned short* Wattnbf = (unsigned short*)carve((size_t)DH * 1024 * 2);
    unsigned short* Woutbf  = (unsigned short*)carve((size_t)VV * DH * 2);
    float*          hTA     = (float*)carve((size_t)BB * DH * 4);
    float*          hTB     = (float*)carve((size_t)BB * DH * 4);
    int*            cnt     = (int*)carve((size_t)TT * NLEAF * 16 * 4);
    float*          pm      = (float*)carve((size_t)NROWS * 250 * 4);
    float*          ps      = (float*)carve((size_t)NROWS * 250 * 4);

    // prep
    k_convert_bf16<<<256, 256, 0, stream>>>(Wattn, Wattnbf, DH * 1024 / 4);
    k_convert_bf16<<<2048, 256, 0, stream>>>(Wout, Woutbf, VV * DH / 4);
    k_convert_hl<<<512, 256, 0, stream>>>(Wih, Wihhi, Wihlo, G4 * DH / 4);
    k_gather_embed_hl<<<NROWS, 128, 0, stream>>>(xseq, emb, ehi, elo);
    k_scan_init<<<128, 256, 0, stream>>>(cnt);

    // x_part^T = (e @ W_ih^T + b_ih + b_hh)^T  -- hi/lo bf16 MFMA (~fp32 accuracy)
    k_mfma_xpart<<<dim3(16, 16), 256, 0, stream>>>(
        ehi, elo, Wihhi, Wihlo, NROWS, G4, DH, bih, bhh, xpartT);

    // sequential LSTM scan (cooperative; register-W, 32-leaf barrier)
    {
        const float* a0 = xpartT; const float* a1 = Whh;
        const float* a2 = h0;     const float* a3 = c0;
        float* a4 = hTA; float* a5 = hTB; float* a6 = Hall;
        unsigned short* a7 = catbf;
        float* a8 = out + (size_t)NROWS * VV;           // hf
        float* a9 = a8 + BB * DH;                       // cf
        int* a10 = cnt;
        void* args[] = {&a0, &a1, &a2, &a3, &a4, &a5, &a6, &a7, &a8, &a9, &a10};
        hipLaunchCooperativeKernel((const void*)k_lstm_scan, dim3(NBLK_SCAN), dim3(512),
                                   args, 0, stream);
    }

    // attention (parallel over all t,b)
    k_attn<<<512, 256, 0, stream>>>(Hall, ctx, catbf);

    // outs = tanh(cat @ W_attn^T)  -> bf16
    k_mfma_gemm<1><<<dim3(4, 16), 256, 0, stream>>>(
        catbf, Wattnbf, NROWS, DH, 1024, nullptr, nullptr, outsbf, nullptr, nullptr);

    // logits = outs @ W_out^T + b_out -> d_out (fp32) + softmax partials
    k_mfma_gemm<2><<<dim3(250, 16), 256, 0, stream>>>(
        outsbf, Woutbf, NROWS, VV, DH, bout, out, nullptr, pm, ps);

    // fused lse + in-place logp
    k_lsesub<<<NROWS, 256, 0, stream>>>(out, pm, ps, 250);
}

// Round 15
// 853.601 us; speedup vs baseline: 1.7512x; 1.0353x over previous
//
#include <hip/hip_runtime.h>
#include <hip/hip_cooperative_groups.h>
#include <cstdint>
#include <cstddef>

namespace cg = cooperative_groups;

#define TT 64
#define BB 32
#define SS 256
#define DH 512
#define VV 32000
#define NROWS 2048   // T*B
#define G4 2048      // 4*DH
#define NBLK_SCAN 256
#define NLEAF 32
#define LEAF_TARGET (NBLK_SCAN / NLEAF)   // 8 arrivals per leaf

typedef __attribute__((ext_vector_type(8))) short short8;
typedef __attribute__((ext_vector_type(4))) float f32x4;

__device__ __forceinline__ unsigned short f2bf(float x) {
    unsigned u = __float_as_uint(x);
    u += 0x7FFFu + ((u >> 16) & 1u);   // RNE
    return (unsigned short)(u >> 16);
}
__device__ __forceinline__ float bf2f(unsigned short u) {
    return __uint_as_float((unsigned)u << 16);
}

__device__ __forceinline__ void gload_lds16(const void* g, void* l) {
    __builtin_amdgcn_global_load_lds(
        (const __attribute__((address_space(1))) unsigned int*)g,
        (__attribute__((address_space(3))) unsigned int*)l, 16, 0, 0);
}

// coherent (agent-scope) dword store -- proven cross-XCD exchange primitive
__device__ __forceinline__ void coh_store(float* p, float v) {
    __hip_atomic_store(p, v, __ATOMIC_RELAXED, __HIP_MEMORY_SCOPE_AGENT);
}

// ---------------- prep kernels ----------------
__global__ void k_convert_bf16(const float* __restrict__ src,
                               unsigned short* __restrict__ dst, int n4) {
    int i = blockIdx.x * blockDim.x + threadIdx.x;
    int stride = gridDim.x * blockDim.x;
    for (; i < n4; i += stride) {
        float4 v = ((const float4*)src)[i];
        ushort4 o;
        o.x = f2bf(v.x); o.y = f2bf(v.y); o.z = f2bf(v.z); o.w = f2bf(v.w);
        ((ushort4*)dst)[i] = o;
    }
}

// fp32 -> hi/lo bf16 planes
__global__ void k_convert_hl(const float* __restrict__ src,
                             unsigned short* __restrict__ hi,
                             unsigned short* __restrict__ lo, int n4) {
    int i = blockIdx.x * blockDim.x + threadIdx.x;
    int stride = gridDim.x * blockDim.x;
    for (; i < n4; i += stride) {
        float4 v = ((const float4*)src)[i];
        ushort4 oh, ol;
        float f[4] = {v.x, v.y, v.z, v.w};
        unsigned short h[4], l[4];
#pragma unroll
        for (int e = 0; e < 4; ++e) {
            h[e] = f2bf(f[e]);
            l[e] = f2bf(f[e] - bf2f(h[e]));
        }
        oh.x = h[0]; oh.y = h[1]; oh.z = h[2]; oh.w = h[3];
        ol.x = l[0]; ol.y = l[1]; ol.z = l[2]; ol.w = l[3];
        ((ushort4*)hi)[i] = oh;
        ((ushort4*)lo)[i] = ol;
    }
}

// gather embedding rows + split into hi/lo bf16 planes; also zero barrier cnt
__global__ void k_gather_embed_hl(const int* __restrict__ xseq,
                                  const float* __restrict__ emb,
                                  unsigned short* __restrict__ ehi,
                                  unsigned short* __restrict__ elo,
                                  int* __restrict__ cnt) {
    int gi = blockIdx.x * blockDim.x + threadIdx.x;
    if (gi < TT * NLEAF * 16) cnt[gi] = 0;
    int r = blockIdx.x;
    int tok = xseq[r];
    const float4* s = (const float4*)(emb + (size_t)tok * DH);
    ushort4* dh = (ushort4*)(ehi + (size_t)r * DH);
    ushort4* dl = (ushort4*)(elo + (size_t)r * DH);
    for (int i = threadIdx.x; i < DH / 4; i += blockDim.x) {
        float4 v = s[i];
        float f[4] = {v.x, v.y, v.z, v.w};
        unsigned short h[4], l[4];
#pragma unroll
        for (int e = 0; e < 4; ++e) {
            h[e] = f2bf(f[e]);
            l[e] = f2bf(f[e] - bf2f(h[e]));
        }
        dh[i] = make_ushort4(h[0], h[1], h[2], h[3]);
        dl[i] = make_ushort4(l[0], l[1], l[2], l[3]);
    }
}

// ---- hi/lo bf16 MFMA GEMM for xpart: Ct[N,M] = (A @ B^T + b1 + b2)^T ----
__global__ __launch_bounds__(256)
void k_mfma_xpart(const unsigned short* __restrict__ Ahi, const unsigned short* __restrict__ Alo,
                  const unsigned short* __restrict__ Bhi, const unsigned short* __restrict__ Blo,
                  int M, int N, int K,
                  const float* __restrict__ b1, const float* __restrict__ b2,
                  float* __restrict__ Ct) {
    __shared__ unsigned short Ah_s[128 * 64];
    __shared__ unsigned short Al_s[128 * 64];
    __shared__ unsigned short Bh_s[128 * 64];
    __shared__ unsigned short Bl_s[128 * 64];

    const int tid = threadIdx.x;
    const int lane = tid & 63;
    const int wid = tid >> 6;
    const int wm = wid >> 1, wn = wid & 1;
    const int mrow0 = blockIdx.y * 128;
    const int ncol0 = blockIdx.x * 128;
    const int lr = lane & 15;
    const int lk = (lane >> 4) * 8;
    const int rw = (lane >> 4) * 4;

    f32x4 acc[4][4] = {};

    for (int kt = 0; kt < K; kt += 64) {
#pragma unroll
        for (int it = 0; it < 4; ++it) {
            int chunk = it * 256 + tid;
            int r = chunk >> 3;
            int c = (chunk & 7) * 8;
            size_t goA = (size_t)(mrow0 + r) * K + kt + c;
            size_t goB = (size_t)(ncol0 + r) * K + kt + c;
            gload_lds16(Ahi + goA, (void*)(Ah_s + chunk * 8));
            gload_lds16(Alo + goA, (void*)(Al_s + chunk * 8));
            gload_lds16(Bhi + goB, (void*)(Bh_s + chunk * 8));
            gload_lds16(Blo + goB, (void*)(Bl_s + chunk * 8));
        }
        __syncthreads();
#pragma unroll
        for (int kk = 0; kk < 2; ++kk) {
            short8 ah[4], al[4], bh[4], bl[4];
#pragma unroll
            for (int i = 0; i < 4; ++i) {
                int offA = (wm * 64 + i * 16 + lr) * 64 + kk * 32 + lk;
                int offB = (wn * 64 + i * 16 + lr) * 64 + kk * 32 + lk;
                ah[i] = *(const short8*)&Ah_s[offA];
                al[i] = *(const short8*)&Al_s[offA];
                bh[i] = *(const short8*)&Bh_s[offB];
                bl[i] = *(const short8*)&Bl_s[offB];
            }
#pragma unroll
            for (int mi = 0; mi < 4; ++mi)
#pragma unroll
                for (int ni = 0; ni < 4; ++ni) {
                    acc[mi][ni] = __builtin_amdgcn_mfma_f32_16x16x32_bf16(
                        ah[mi], bh[ni], acc[mi][ni], 0, 0, 0);
                    acc[mi][ni] = __builtin_amdgcn_mfma_f32_16x16x32_bf16(
                        ah[mi], bl[ni], acc[mi][ni], 0, 0, 0);
                    acc[mi][ni] = __builtin_amdgcn_mfma_f32_16x16x32_bf16(
                        al[mi], bh[ni], acc[mi][ni], 0, 0, 0);
                }
        }
        __syncthreads();
    }

    // transposed epilogue: Ct[col][row], rows r=0..3 contiguous -> float4 store
#pragma unroll
    for (int ni = 0; ni < 4; ++ni) {
        int col = ncol0 + wn * 64 + ni * 16 + lr;
        float bs = b1[col] + b2[col];
#pragma unroll
        for (int mi = 0; mi < 4; ++mi) {
            int grow0 = mrow0 + wm * 64 + mi * 16 + rw;
            float4 o;
            o.x = acc[mi][ni][0] + bs;
            o.y = acc[mi][ni][1] + bs;
            o.z = acc[mi][ni][2] + bs;
            o.w = acc[mi][ni][3] + bs;
            *(float4*)&Ct[(size_t)col * M + grow0] = o;
        }
    }
}

// ---------------- MFMA GEMM: C[M,N] = A[M,K] @ B[N,K]^T (+epilogue) ----------------
template <int EPI>
__global__ __launch_bounds__(256)
void k_mfma_gemm(const unsigned short* __restrict__ A,
                 const unsigned short* __restrict__ B,
                 int M, int N, int K,
                 const float* __restrict__ bias,
                 float* __restrict__ Cf,
                 unsigned short* __restrict__ Cbf,
                 float* __restrict__ pm, float* __restrict__ ps) {
    __shared__ unsigned short A_s[128 * 64];
    __shared__ unsigned short B_s[128 * 64];
    __shared__ float part_m[2][128];
    __shared__ float part_s[2][128];

    const int tid = threadIdx.x;
    const int lane = tid & 63;
    const int wid = tid >> 6;
    const int wm = wid >> 1, wn = wid & 1;
    const int mrow0 = blockIdx.y * 128;
    const int ncol0 = blockIdx.x * 128;
    const int lr = lane & 15;
    const int lk = (lane >> 4) * 8;
    const int rw = (lane >> 4) * 4;

    f32x4 acc[4][4] = {};

    for (int kt = 0; kt < K; kt += 64) {
#pragma unroll
        for (int it = 0; it < 4; ++it) {
            int chunk = it * 256 + tid;
            int r = chunk >> 3;
            int c = (chunk & 7) * 8;
            gload_lds16(A + (size_t)(mrow0 + r) * K + kt + c, (void*)(A_s + chunk * 8));
            gload_lds16(B + (size_t)(ncol0 + r) * K + kt + c, (void*)(B_s + chunk * 8));
        }
        __syncthreads();
#pragma unroll
        for (int kk = 0; kk < 2; ++kk) {
            short8 afr[4], bfr[4];
#pragma unroll
            for (int i = 0; i < 4; ++i) {
                afr[i] = *(const short8*)&A_s[(wm * 64 + i * 16 + lr) * 64 + kk * 32 + lk];
                bfr[i] = *(const short8*)&B_s[(wn * 64 + i * 16 + lr) * 64 + kk * 32 + lk];
            }
#pragma unroll
            for (int mi = 0; mi < 4; ++mi)
#pragma unroll
                for (int ni = 0; ni < 4; ++ni)
                    acc[mi][ni] = __builtin_amdgcn_mfma_f32_16x16x32_bf16(
                        afr[mi], bfr[ni], acc[mi][ni], 0, 0, 0);
        }
        __syncthreads();
    }

    if constexpr (EPI == 1) {
#pragma unroll
        for (int ni = 0; ni < 4; ++ni) {
            int col = ncol0 + wn * 64 + ni * 16 + lr;
#pragma unroll
            for (int mi = 0; mi < 4; ++mi)
#pragma unroll
                for (int r = 0; r < 4; ++r) {
                    int grow = mrow0 + wm * 64 + mi * 16 + rw + r;
                    Cbf[(size_t)grow * N + col] = f2bf(tanhf(acc[mi][ni][r]));
                }
        }
    } else {
        float bv[4];
#pragma unroll
        for (int ni = 0; ni < 4; ++ni) bv[ni] = bias[ncol0 + wn * 64 + ni * 16 + lr];
#pragma unroll
        for (int mi = 0; mi < 4; ++mi) {
#pragma unroll
            for (int r = 0; r < 4; ++r) {
                int grow = mrow0 + wm * 64 + mi * 16 + rw + r;
                float v[4];
                float mx = -1e30f;
#pragma unroll
                for (int ni = 0; ni < 4; ++ni) {
                    v[ni] = acc[mi][ni][r] + bv[ni];
                    int col = ncol0 + wn * 64 + ni * 16 + lr;
                    Cf[(size_t)grow * N + col] = v[ni];
                    mx = fmaxf(mx, v[ni]);
                }
#pragma unroll
                for (int d = 1; d <= 8; d <<= 1) mx = fmaxf(mx, __shfl_xor(mx, d));
                float ssum = 0.f;
#pragma unroll
                for (int ni = 0; ni < 4; ++ni) ssum += __expf(v[ni] - mx);
#pragma unroll
                for (int d = 1; d <= 8; d <<= 1) ssum += __shfl_xor(ssum, d);
                if (lr == 0) {
                    int lrow = wm * 64 + mi * 16 + rw + r;
                    part_m[wn][lrow] = mx;
                    part_s[wn][lrow] = ssum;
                }
            }
        }
        __syncthreads();
        if (tid < 128) {
            float m0v = part_m[0][tid], m1v = part_m[1][tid];
            float mm = fmaxf(m0v, m1v);
            float ssum = part_s[0][tid] * __expf(m0v - mm) + part_s[1][tid] * __expf(m1v - mm);
            int grow = mrow0 + tid;
            pm[(size_t)grow * gridDim.x + blockIdx.x] = mm;
            ps[(size_t)grow * gridDim.x + blockIdx.x] = ssum;
        }
    }
}

// ---------------- LSTM scan: register-W ks-split dot, 512 threads ---------------
// r13/r14-proven structure. r15 perf tweaks (same math):
// (1) barrier: post arrival -> prefetch next xg under propagation -> pure-spin poll
// (2) stage: counted vmcnt(4) split -> LDS writes overlap load returns
__global__ __launch_bounds__(512, 2)
void k_lstm_scan(const float* __restrict__ xpartT, const float* __restrict__ Whh,
                 const float* __restrict__ h0, const float* __restrict__ c0,
                 float* __restrict__ hTA, float* __restrict__ hTB,
                 float* __restrict__ Hall, unsigned short* __restrict__ catbuf,
                 float* __restrict__ hf, float* __restrict__ cf,
                 int* __restrict__ cnt) {
    __shared__ __align__(16) float h_lds[BB * 8 * 17 * 4];   // 69.6 KB

    const int tid = threadIdx.x;
    const int jl = tid >> 8;             // 0..1
    const int bq = (tid >> 4) & 15;      // handles b = bq, bq+16
    const int ks = tid & 15;             // k-slice: cols ks*32 .. ks*32+31
    const int jj = blockIdx.x * 2 + jl;

    // --- prologue: this thread's W slice into registers (4 gates x 32 cols) ---
    f32x4 wreg[4][8];
#pragma unroll
    for (int g = 0; g < 4; ++g) {
        const float* wp = Whh + (size_t)(g * DH + jj) * DH + ks * 32;
#pragma unroll
        for (int r = 0; r < 8; ++r)
            wreg[g][r] = *(const f32x4*)(wp + r * 4);
    }

    float creg0 = c0[(size_t)bq * DH + jj];          // used only by ks==0
    float creg1 = c0[(size_t)(bq + 16) * DH + jj];

    // xg prefetch for t=0
    float xg0a = 0.f, xg1a = 0.f, xg2a = 0.f, xg3a = 0.f;
    float xg0b = 0.f, xg1b = 0.f, xg2b = 0.f, xg3b = 0.f;
    if (ks == 0) {
        const float* xt = xpartT;
        xg0a = xt[(size_t)(0 * DH + jj) * NROWS + bq];
        xg1a = xt[(size_t)(1 * DH + jj) * NROWS + bq];
        xg2a = xt[(size_t)(2 * DH + jj) * NROWS + bq];
        xg3a = xt[(size_t)(3 * DH + jj) * NROWS + bq];
        xg0b = xt[(size_t)(0 * DH + jj) * NROWS + bq + 16];
        xg1b = xt[(size_t)(1 * DH + jj) * NROWS + bq + 16];
        xg2b = xt[(size_t)(2 * DH + jj) * NROWS + bq + 16];
        xg3b = xt[(size_t)(3 * DH + jj) * NROWS + bq + 16];
    }

    for (int t = 0; t < TT; ++t) {
        const float* hR = (t == 0) ? h0 : ((t & 1) ? hTA : hTB);   // r5 parity
        // ---- stage h: 8 uncached dwordx4/thread, split drain ----
        {
            f32x4 v[8];
#pragma unroll
            for (int q = 0; q < 8; ++q)
                asm volatile("global_load_dwordx4 %0, %1, off sc0 sc1"
                             : "=&v"(v[q]) : "v"(hR + (q * 512 + tid) * 4));
            asm volatile("s_waitcnt vmcnt(4)" ::: "memory");
            __builtin_amdgcn_sched_barrier(0);
#pragma unroll
            for (int q = 0; q < 4; ++q) {
                int f = q * 512 + tid;
                int b2 = f >> 7;
                int ks2 = (f & 127) >> 3;
                int r2 = f & 7;
                *(f32x4*)&h_lds[((b2 * 8 + r2) * 17 + ks2) * 4] = v[q];
            }
            asm volatile("s_waitcnt vmcnt(0)" ::: "memory");
            __builtin_amdgcn_sched_barrier(0);
#pragma unroll
            for (int q = 4; q < 8; ++q) {
                int f = q * 512 + tid;
                int b2 = f >> 7;
                int ks2 = (f & 127) >> 3;
                int r2 = f & 7;
                *(f32x4*)&h_lds[((b2 * 8 + r2) * 17 + ks2) * 4] = v[q];
            }
        }
        __syncthreads();

        // ---- partial dot: W regs x LDS h, 2 b-values, ks-slice of 32 cols ----
        float a0a = 0.f, a1a = 0.f, a2a = 0.f, a3a = 0.f;
        float a0b = 0.f, a1b = 0.f, a2b = 0.f, a3b = 0.f;
#pragma unroll
        for (int r = 0; r < 8; ++r) {
            f32x4 ha = *(const f32x4*)&h_lds[((bq * 8 + r) * 17 + ks) * 4];
            f32x4 hb = *(const f32x4*)&h_lds[(((bq + 16) * 8 + r) * 17 + ks) * 4];
            a0a += wreg[0][r][0] * ha[0] + wreg[0][r][1] * ha[1]
                 + wreg[0][r][2] * ha[2] + wreg[0][r][3] * ha[3];
            a1a += wreg[1][r][0] * ha[0] + wreg[1][r][1] * ha[1]
                 + wreg[1][r][2] * ha[2] + wreg[1][r][3] * ha[3];
            a2a += wreg[2][r][0] * ha[0] + wreg[2][r][1] * ha[1]
                 + wreg[2][r][2] * ha[2] + wreg[2][r][3] * ha[3];
            a3a += wreg[3][r][0] * ha[0] + wreg[3][r][1] * ha[1]
                 + wreg[3][r][2] * ha[2] + wreg[3][r][3] * ha[3];
            a0b += wreg[0][r][0] * hb[0] + wreg[0][r][1] * hb[1]
                 + wreg[0][r][2] * hb[2] + wreg[0][r][3] * hb[3];
            a1b += wreg[1][r][0] * hb[0] + wreg[1][r][1] * hb[1]
                 + wreg[1][r][2] * hb[2] + wreg[1][r][3] * hb[3];
            a2b += wreg[2][r][0] * hb[0] + wreg[2][r][1] * hb[1]
                 + wreg[2][r][2] * hb[2] + wreg[2][r][3] * hb[3];
            a3b += wreg[3][r][0] * hb[0] + wreg[3][r][1] * hb[1]
                 + wreg[3][r][2] * hb[2] + wreg[3][r][3] * hb[3];
        }
        // reduce over ks (lane bits 0..3)
#pragma unroll
        for (int d = 1; d <= 8; d <<= 1) {
            a0a += __shfl_xor(a0a, d); a1a += __shfl_xor(a1a, d);
            a2a += __shfl_xor(a2a, d); a3a += __shfl_xor(a3a, d);
            a0b += __shfl_xor(a0b, d); a1b += __shfl_xor(a1b, d);
            a2b += __shfl_xor(a2b, d); a3b += __shfl_xor(a3b, d);
        }

        if (ks == 0) {
            float* wb = (t & 1) ? hTB : hTA;          // r5 writer parity
#pragma unroll
            for (int bh = 0; bh < 2; ++bh) {
                int b = bh ? bq + 16 : bq;
                float gi = (bh ? a0b : a0a) + (bh ? xg0b : xg0a);
                float gf = (bh ? a1b : a1a) + (bh ? xg1b : xg1a);
                float gg = (bh ? a2b : a2a) + (bh ? xg2b : xg2a);
                float go = (bh ? a3b : a3a) + (bh ? xg3b : xg3a);
                float si = 1.f / (1.f + __expf(-gi));
                float sf = 1.f / (1.f + __expf(-gf));
                float tg = tanhf(gg);
                float so = 1.f / (1.f + __expf(-go));
                float cc = bh ? creg1 : creg0;
                cc = sf * cc + si * tg;
                float hn = so * tanhf(cc);
                if (bh) creg1 = cc; else creg0 = cc;

                coh_store(&wb[(size_t)b * DH + jj], hn);  // [b][j] layout
                int row = t * BB + b;
                Hall[(size_t)row * DH + jj] = hn;
                catbuf[(size_t)row * 1024 + jj] = f2bf(hn);
                if (t == TT - 1) {
                    hf[(size_t)b * DH + jj] = hn;
                    cf[(size_t)b * DH + jj] = cc;
                }
            }
        }

        // ---- device barrier: post -> prefetch next xg -> spin poll ----
        __syncthreads();   // drains vmcnt before s_barrier -> h stores done
        if (tid == 0) {
            asm volatile("s_waitcnt vmcnt(0)" ::: "memory");
            __hip_atomic_fetch_add(&cnt[t * (NLEAF * 16) + (blockIdx.x & (NLEAF - 1)) * 16], 1,
                                   __ATOMIC_RELAXED, __HIP_MEMORY_SCOPE_AGENT);
        }
        // prefetch next step's xg while the arrival propagates
        if (ks == 0 && t + 1 < TT) {
            const float* xt = xpartT + (size_t)(t + 1) * BB;
            xg0a = xt[(size_t)(0 * DH + jj) * NROWS + bq];
            xg1a = xt[(size_t)(1 * DH + jj) * NROWS + bq];
            xg2a = xt[(size_t)(2 * DH + jj) * NROWS + bq];
            xg3a = xt[(size_t)(3 * DH + jj) * NROWS + bq];
            xg0b = xt[(size_t)(0 * DH + jj) * NROWS + bq + 16];
            xg1b = xt[(size_t)(1 * DH + jj) * NROWS + bq + 16];
            xg2b = xt[(size_t)(2 * DH + jj) * NROWS + bq + 16];
            xg3b = xt[(size_t)(3 * DH + jj) * NROWS + bq + 16];
        }
        if (tid < NLEAF) {
            while (__hip_atomic_load(&cnt[t * (NLEAF * 16) + tid * 16], __ATOMIC_RELAXED,
                                     __HIP_MEMORY_SCOPE_AGENT) < LEAF_TARGET) {
                // pure spin: read-shared L3 loads, no sleep quantum
            }
        }
        __syncthreads();
    }
}

// ---------------- attention: scores -> softmax -> wctx (per (b, 4 t's)) ----------------
__global__ __launch_bounds__(256)
void k_attn(const float* __restrict__ Hall, const float* __restrict__ ctx,
            unsigned short* __restrict__ catbuf) {
    __shared__ float h4[4][DH];
    __shared__ float p_lds[4][SS];
    __shared__ float l_lds[4];

    const int tid = threadIdx.x;
    const int b = blockIdx.x & 31;
    const int tg = blockIdx.x >> 5;

    for (int i = tid; i < 4 * DH / 4; i += 256) {
        int e = i * 4;
        int ti = e >> 9, k = e & 511;
        float4 v = *(const float4*)(Hall + ((size_t)((tg * 4 + ti) * BB + b)) * DH + k);
        h4[ti][k + 0] = v.x; h4[ti][k + 1] = v.y; h4[ti][k + 2] = v.z; h4[ti][k + 3] = v.w;
    }
    __syncthreads();

    {
        int s = tid;
        float acc[4] = {0.f, 0.f, 0.f, 0.f};
        const float4* cp = (const float4*)(ctx + ((size_t)b * SS + s) * DH);
        for (int kc = 0; kc < DH / 4; ++kc) {
            float4 cv = cp[kc];
#pragma unroll
            for (int i = 0; i < 4; ++i) {
                float4 hv = *(const float4*)&h4[i][kc * 4];
                acc[i] += cv.x * hv.x + cv.y * hv.y + cv.z * hv.z + cv.w * hv.w;
            }
        }
#pragma unroll
        for (int i = 0; i < 4; ++i) p_lds[i][s] = acc[i];
    }
    __syncthreads();

    {
        int w = tid >> 6, l = tid & 63;
        float v0 = p_lds[w][l], v1 = p_lds[w][l + 64];
        float v2 = p_lds[w][l + 128], v3 = p_lds[w][l + 192];
        float mx = fmaxf(fmaxf(v0, v1), fmaxf(v2, v3));
        for (int d = 1; d < 64; d <<= 1) mx = fmaxf(mx, __shfl_xor(mx, d));
        float e0 = __expf(v0 - mx), e1 = __expf(v1 - mx);
        float e2 = __expf(v2 - mx), e3 = __expf(v3 - mx);
        float ssum = e0 + e1 + e2 + e3;
        for (int d = 1; d < 64; d <<= 1) ssum += __shfl_xor(ssum, d);
        p_lds[w][l] = e0; p_lds[w][l + 64] = e1;
        p_lds[w][l + 128] = e2; p_lds[w][l + 192] = e3;
        if (l == 0) l_lds[w] = ssum;
    }
    __syncthreads();

    {
        int d0 = tid * 2;
        float accx[4], accy[4];
#pragma unroll
        for (int i = 0; i < 4; ++i) { accx[i] = 0.f; accy[i] = 0.f; }
        const float* cb = ctx + (size_t)b * SS * DH + d0;
        for (int s = 0; s < SS; ++s) {
            float2 cv = *(const float2*)(cb + (size_t)s * DH);
#pragma unroll
            for (int i = 0; i < 4; ++i) {
                float p = p_lds[i][s];
                accx[i] += p * cv.x;
                accy[i] += p * cv.y;
            }
        }
#pragma unroll
        for (int i = 0; i < 4; ++i) {
            float inv = 1.f / l_lds[i];
            int row = (tg * 4 + i) * BB + b;
            unsigned pack = (unsigned)f2bf(accx[i] * inv) | ((unsigned)f2bf(accy[i] * inv) << 16);
            *(unsigned*)&catbuf[(size_t)row * 1024 + DH + d0] = pack;
        }
    }
}

// ---------------- fused lse + subtract (one block per row) ----------------
__global__ __launch_bounds__(256)
void k_lsesub(float* __restrict__ logp, const float* __restrict__ pm,
              const float* __restrict__ ps, int nt) {
    __shared__ float sL;
    const int row = blockIdx.x;
    const int tid = threadIdx.x;
    if (tid < 64) {
        const float* pmr = pm + (size_t)row * nt;
        const float* psr = ps + (size_t)row * nt;
        float m = -1e30f;
        for (int i = tid; i < nt; i += 64) m = fmaxf(m, pmr[i]);
        for (int d = 1; d < 64; d <<= 1) m = fmaxf(m, __shfl_xor(m, d));
        float s = 0.f;
        for (int i = tid; i < nt; i += 64) s += psr[i] * __expf(pmr[i] - m);
        for (int d = 1; d < 64; d <<= 1) s += __shfl_xor(s, d);
        if (tid == 0) sL = m + logf(s);
    }
    __syncthreads();
    float L = sL;
    float4* p = (float4*)(logp + (size_t)row * VV);
    for (int i = tid; i < VV / 4; i += 256) {
        float4 v = p[i];
        v.x -= L; v.y -= L; v.z -= L; v.w -= L;
        p[i] = v;
    }
}

// ---------------- host launch ----------------
extern "C" void kernel_launch(void* const* d_in, const int* in_sizes, int n_in,
                              void* d_out, int out_size, void* d_ws, size_t ws_size,
                              hipStream_t stream) {
    const int*   xseq  = (const int*)d_in[0];
    const float* h0    = (const float*)d_in[1];
    const float* c0    = (const float*)d_in[2];
    const float* ctx   = (const float*)d_in[3];
    const float* emb   = (const float*)d_in[4];
    const float* Wih   = (const float*)d_in[5];
    const float* Whh   = (const float*)d_in[6];
    const float* bih   = (const float*)d_in[7];
    const float* bhh   = (const float*)d_in[8];
    const float* Wattn = (const float*)d_in[9];
    const float* Wout  = (const float*)d_in[10];
    const float* bout  = (const float*)d_in[11];
    float* out = (float*)d_out;

    char* wptr = (char*)d_ws;
    auto carve = [&](size_t bytes) {
        char* p = wptr;
        wptr += (bytes + 255) & ~(size_t)255;
        return p;
    };
    float*          xpartT  = (float*)carve((size_t)NROWS * G4 * 4);
    float*          Hall    = (float*)carve((size_t)NROWS * DH * 4);
    unsigned short* catbf   = (unsigned short*)carve((size_t)NROWS * 1024 * 2);
    unsigned short* outsbf  = (unsigned short*)carve((size_t)NROWS * DH * 2);
    unsigned short* ehi     = (unsigned short*)carve((size_t)NROWS * DH * 2);
    unsigned short* elo     = (unsigned short*)carve((size_t)NROWS * DH * 2);
    unsigned short* Wihhi   = (unsigned short*)carve((size_t)G4 * DH * 2);
    unsigned short* Wihlo   = (unsigned short*)carve((size_t)G4 * DH * 2);
    unsigned short* Wattnbf = (unsigned short*)carve((size_t)DH * 1024 * 2);
    unsigned short* Woutbf  = (unsigned short*)carve((size_t)VV * DH * 2);
    float*          hTA     = (float*)carve((size_t)BB * DH * 4);
    float*          hTB     = (float*)carve((size_t)BB * DH * 4);
    int*            cnt     = (int*)carve((size_t)TT * NLEAF * 16 * 4);
    float*          pm      = (float*)carve((size_t)NROWS * 250 * 4);
    float*          ps      = (float*)carve((size_t)NROWS * 250 * 4);

    // prep
    k_convert_bf16<<<256, 256, 0, stream>>>(Wattn, Wattnbf, DH * 1024 / 4);
    k_convert_bf16<<<2048, 256, 0, stream>>>(Wout, Woutbf, VV * DH / 4);
    k_convert_hl<<<512, 256, 0, stream>>>(Wih, Wihhi, Wihlo, G4 * DH / 4);
    k_gather_embed_hl<<<NROWS, 128, 0, stream>>>(xseq, emb, ehi, elo, cnt);

    // x_part^T = (e @ W_ih^T + b_ih + b_hh)^T  -- hi/lo bf16 MFMA (~fp32 accuracy)
    k_mfma_xpart<<<dim3(16, 16), 256, 0, stream>>>(
        ehi, elo, Wihhi, Wihlo, NROWS, G4, DH, bih, bhh, xpartT);

    // sequential LSTM scan (cooperative; register-W, 32-leaf spin barrier)
    {
        const float* a0 = xpartT; const float* a1 = Whh;
        const float* a2 = h0;     const float* a3 = c0;
        float* a4 = hTA; float* a5 = hTB; float* a6 = Hall;
        unsigned short* a7 = catbf;
        float* a8 = out + (size_t)NROWS * VV;           // hf
        float* a9 = a8 + BB * DH;                       // cf
        int* a10 = cnt;
        void* args[] = {&a0, &a1, &a2, &a3, &a4, &a5, &a6, &a7, &a8, &a9, &a10};
        hipLaunchCooperativeKernel((const void*)k_lstm_scan, dim3(NBLK_SCAN), dim3(512),
                                   args, 0, stream);
    }

    // attention (parallel over all t,b)
    k_attn<<<512, 256, 0, stream>>>(Hall, ctx, catbf);

    // outs = tanh(cat @ W_attn^T)  -> bf16
    k_mfma_gemm<1><<<dim3(4, 16), 256, 0, stream>>>(
        catbf, Wattnbf, NROWS, DH, 1024, nullptr, nullptr, outsbf, nullptr, nullptr);

    // logits = outs @ W_out^T + b_out -> d_out (fp32) + softmax partials
    k_mfma_gemm<2><<<dim3(250, 16), 256, 0, stream>>>(
        outsbf, Woutbf, NROWS, VV, DH, bout, out, nullptr, pm, ps);

    // fused lse + in-place logp
    k_lsesub<<<NROWS, 256, 0, stream>>>(out, pm, ps, 250);
}

// Round 16
// 834.505 us; speedup vs baseline: 1.7913x; 1.0229x over previous
//
#include <hip/hip_runtime.h>
#include <hip/hip_cooperative_groups.h>
#include <cstdint>
#include <cstddef>

namespace cg = cooperative_groups;

#define TT 64
#define BB 32
#define SS 256
#define DH 512
#define VV 32000
#define NROWS 2048   // T*B
#define G4 2048      // 4*DH
#define NBLK_SCAN 256
#define NLEAF 32
#define LEAF_TARGET (NBLK_SCAN / NLEAF)   // 8 arrivals per leaf
#define NTILE_N 250                        // VV/128
#define NTILE_M 16                         // NROWS/128

typedef __attribute__((ext_vector_type(8))) short short8;
typedef __attribute__((ext_vector_type(8))) unsigned short ushort8v;
typedef __attribute__((ext_vector_type(4))) float f32x4;

__device__ __forceinline__ unsigned short f2bf(float x) {
    unsigned u = __float_as_uint(x);
    u += 0x7FFFu + ((u >> 16) & 1u);   // RNE
    return (unsigned short)(u >> 16);
}
__device__ __forceinline__ float bf2f(unsigned short u) {
    return __uint_as_float((unsigned)u << 16);
}

__device__ __forceinline__ void gload_lds16(const void* g, void* l) {
    __builtin_amdgcn_global_load_lds(
        (const __attribute__((address_space(1))) unsigned int*)g,
        (__attribute__((address_space(3))) unsigned int*)l, 16, 0, 0);
}

// coherent (agent-scope) dword store -- proven cross-XCD exchange primitive
__device__ __forceinline__ void coh_store(float* p, float v) {
    __hip_atomic_store(p, v, __ATOMIC_RELAXED, __HIP_MEMORY_SCOPE_AGENT);
}

// ---------------- prep kernels ----------------
__global__ void k_convert_bf16(const float* __restrict__ src,
                               unsigned short* __restrict__ dst, int n4) {
    int i = blockIdx.x * blockDim.x + threadIdx.x;
    int stride = gridDim.x * blockDim.x;
    for (; i < n4; i += stride) {
        float4 v = ((const float4*)src)[i];
        ushort4 o;
        o.x = f2bf(v.x); o.y = f2bf(v.y); o.z = f2bf(v.z); o.w = f2bf(v.w);
        ((ushort4*)dst)[i] = o;
    }
}

// fp32 -> hi/lo bf16 planes
__global__ void k_convert_hl(const float* __restrict__ src,
                             unsigned short* __restrict__ hi,
                             unsigned short* __restrict__ lo, int n4) {
    int i = blockIdx.x * blockDim.x + threadIdx.x;
    int stride = gridDim.x * blockDim.x;
    for (; i < n4; i += stride) {
        float4 v = ((const float4*)src)[i];
        ushort4 oh, ol;
        float f[4] = {v.x, v.y, v.z, v.w};
        unsigned short h[4], l[4];
#pragma unroll
        for (int e = 0; e < 4; ++e) {
            h[e] = f2bf(f[e]);
            l[e] = f2bf(f[e] - bf2f(h[e]));
        }
        oh.x = h[0]; oh.y = h[1]; oh.z = h[2]; oh.w = h[3];
        ol.x = l[0]; ol.y = l[1]; ol.z = l[2]; ol.w = l[3];
        ((ushort4*)hi)[i] = oh;
        ((ushort4*)lo)[i] = ol;
    }
}

// gather embedding rows + split into hi/lo bf16 planes; also zero barrier cnt
__global__ void k_gather_embed_hl(const int* __restrict__ xseq,
                                  const float* __restrict__ emb,
                                  unsigned short* __restrict__ ehi,
                                  unsigned short* __restrict__ elo,
                                  int* __restrict__ cnt) {
    int gi = blockIdx.x * blockDim.x + threadIdx.x;
    if (gi < TT * NLEAF * 16) cnt[gi] = 0;
    int r = blockIdx.x;
    int tok = xseq[r];
    const float4* s = (const float4*)(emb + (size_t)tok * DH);
    ushort4* dh = (ushort4*)(ehi + (size_t)r * DH);
    ushort4* dl = (ushort4*)(elo + (size_t)r * DH);
    for (int i = threadIdx.x; i < DH / 4; i += blockDim.x) {
        float4 v = s[i];
        float f[4] = {v.x, v.y, v.z, v.w};
        unsigned short h[4], l[4];
#pragma unroll
        for (int e = 0; e < 4; ++e) {
            h[e] = f2bf(f[e]);
            l[e] = f2bf(f[e] - bf2f(h[e]));
        }
        dh[i] = make_ushort4(h[0], h[1], h[2], h[3]);
        dl[i] = make_ushort4(l[0], l[1], l[2], l[3]);
    }
}

// ---- hi/lo bf16 MFMA GEMM for xpart: Ct[N,M] = (A @ B^T + b1 + b2)^T ----
__global__ __launch_bounds__(256)
void k_mfma_xpart(const unsigned short* __restrict__ Ahi, const unsigned short* __restrict__ Alo,
                  const unsigned short* __restrict__ Bhi, const unsigned short* __restrict__ Blo,
                  int M, int N, int K,
                  const float* __restrict__ b1, const float* __restrict__ b2,
                  float* __restrict__ Ct) {
    __shared__ unsigned short Ah_s[128 * 64];
    __shared__ unsigned short Al_s[128 * 64];
    __shared__ unsigned short Bh_s[128 * 64];
    __shared__ unsigned short Bl_s[128 * 64];

    const int tid = threadIdx.x;
    const int lane = tid & 63;
    const int wid = tid >> 6;
    const int wm = wid >> 1, wn = wid & 1;
    const int mrow0 = blockIdx.y * 128;
    const int ncol0 = blockIdx.x * 128;
    const int lr = lane & 15;
    const int lk = (lane >> 4) * 8;
    const int rw = (lane >> 4) * 4;

    f32x4 acc[4][4] = {};

    for (int kt = 0; kt < K; kt += 64) {
#pragma unroll
        for (int it = 0; it < 4; ++it) {
            int chunk = it * 256 + tid;
            int r = chunk >> 3;
            int c = (chunk & 7) * 8;
            size_t goA = (size_t)(mrow0 + r) * K + kt + c;
            size_t goB = (size_t)(ncol0 + r) * K + kt + c;
            gload_lds16(Ahi + goA, (void*)(Ah_s + chunk * 8));
            gload_lds16(Alo + goA, (void*)(Al_s + chunk * 8));
            gload_lds16(Bhi + goB, (void*)(Bh_s + chunk * 8));
            gload_lds16(Blo + goB, (void*)(Bl_s + chunk * 8));
        }
        __syncthreads();
#pragma unroll
        for (int kk = 0; kk < 2; ++kk) {
            short8 ah[4], al[4], bh[4], bl[4];
#pragma unroll
            for (int i = 0; i < 4; ++i) {
                int offA = (wm * 64 + i * 16 + lr) * 64 + kk * 32 + lk;
                int offB = (wn * 64 + i * 16 + lr) * 64 + kk * 32 + lk;
                ah[i] = *(const short8*)&Ah_s[offA];
                al[i] = *(const short8*)&Al_s[offA];
                bh[i] = *(const short8*)&Bh_s[offB];
                bl[i] = *(const short8*)&Bl_s[offB];
            }
#pragma unroll
            for (int mi = 0; mi < 4; ++mi)
#pragma unroll
                for (int ni = 0; ni < 4; ++ni) {
                    acc[mi][ni] = __builtin_amdgcn_mfma_f32_16x16x32_bf16(
                        ah[mi], bh[ni], acc[mi][ni], 0, 0, 0);
                    acc[mi][ni] = __builtin_amdgcn_mfma_f32_16x16x32_bf16(
                        ah[mi], bl[ni], acc[mi][ni], 0, 0, 0);
                    acc[mi][ni] = __builtin_amdgcn_mfma_f32_16x16x32_bf16(
                        al[mi], bh[ni], acc[mi][ni], 0, 0, 0);
                }
        }
        __syncthreads();
    }

    // transposed epilogue: Ct[col][row], rows r=0..3 contiguous -> float4 store
#pragma unroll
    for (int ni = 0; ni < 4; ++ni) {
        int col = ncol0 + wn * 64 + ni * 16 + lr;
        float bs = b1[col] + b2[col];
#pragma unroll
        for (int mi = 0; mi < 4; ++mi) {
            int grow0 = mrow0 + wm * 64 + mi * 16 + rw;
            float4 o;
            o.x = acc[mi][ni][0] + bs;
            o.y = acc[mi][ni][1] + bs;
            o.z = acc[mi][ni][2] + bs;
            o.w = acc[mi][ni][3] + bs;
            *(float4*)&Ct[(size_t)col * M + grow0] = o;
        }
    }
}

// ---------------- MFMA GEMM: C[M,N] = A[M,K] @ B[N,K]^T (+epilogue) ----------------
// EPI 1: Cbf = bf16(tanh(acc)), 2D grid.
// EPI 2: Cf fp32 + softmax partials, 1D grid 4000 with XCD swizzle.
// EPI 3: Cbf bf16 logits + softmax partials (partials from fp32 v), 1D swizzled.
template <int EPI>
__global__ __launch_bounds__(256)
void k_mfma_gemm(const unsigned short* __restrict__ A,
                 const unsigned short* __restrict__ B,
                 int M, int N, int K,
                 const float* __restrict__ bias,
                 float* __restrict__ Cf,
                 unsigned short* __restrict__ Cbf,
                 float* __restrict__ pm, float* __restrict__ ps) {
    __shared__ unsigned short A_s[128 * 64];
    __shared__ unsigned short B_s[128 * 64];
    __shared__ float part_m[2][128];
    __shared__ float part_s[2][128];

    const int tid = threadIdx.x;
    const int lane = tid & 63;
    const int wid = tid >> 6;
    const int wm = wid >> 1, wn = wid & 1;

    int bx, by;
    if constexpr (EPI >= 2) {
        // bijective XCD swizzle: 4000 blocks = 8 XCDs x 500 contiguous tiles
        int lin = blockIdx.x;
        int swz = (lin & 7) * 500 + (lin >> 3);
        by = swz / NTILE_N;
        bx = swz - by * NTILE_N;
    } else {
        bx = blockIdx.x; by = blockIdx.y;
    }
    const int mrow0 = by * 128;
    const int ncol0 = bx * 128;
    const int lr = lane & 15;
    const int lk = (lane >> 4) * 8;
    const int rw = (lane >> 4) * 4;

    f32x4 acc[4][4] = {};

    for (int kt = 0; kt < K; kt += 64) {
#pragma unroll
        for (int it = 0; it < 4; ++it) {
            int chunk = it * 256 + tid;
            int r = chunk >> 3;
            int c = (chunk & 7) * 8;
            gload_lds16(A + (size_t)(mrow0 + r) * K + kt + c, (void*)(A_s + chunk * 8));
            gload_lds16(B + (size_t)(ncol0 + r) * K + kt + c, (void*)(B_s + chunk * 8));
        }
        __syncthreads();
#pragma unroll
        for (int kk = 0; kk < 2; ++kk) {
            short8 afr[4], bfr[4];
#pragma unroll
            for (int i = 0; i < 4; ++i) {
                afr[i] = *(const short8*)&A_s[(wm * 64 + i * 16 + lr) * 64 + kk * 32 + lk];
                bfr[i] = *(const short8*)&B_s[(wn * 64 + i * 16 + lr) * 64 + kk * 32 + lk];
            }
#pragma unroll
            for (int mi = 0; mi < 4; ++mi)
#pragma unroll
                for (int ni = 0; ni < 4; ++ni)
                    acc[mi][ni] = __builtin_amdgcn_mfma_f32_16x16x32_bf16(
                        afr[mi], bfr[ni], acc[mi][ni], 0, 0, 0);
        }
        __syncthreads();
    }

    if constexpr (EPI == 1) {
#pragma unroll
        for (int ni = 0; ni < 4; ++ni) {
            int col = ncol0 + wn * 64 + ni * 16 + lr;
#pragma unroll
            for (int mi = 0; mi < 4; ++mi)
#pragma unroll
                for (int r = 0; r < 4; ++r) {
                    int grow = mrow0 + wm * 64 + mi * 16 + rw + r;
                    Cbf[(size_t)grow * N + col] = f2bf(tanhf(acc[mi][ni][r]));
                }
        }
    } else {
        float bv[4];
#pragma unroll
        for (int ni = 0; ni < 4; ++ni) bv[ni] = bias[ncol0 + wn * 64 + ni * 16 + lr];
#pragma unroll
        for (int mi = 0; mi < 4; ++mi) {
#pragma unroll
            for (int r = 0; r < 4; ++r) {
                int grow = mrow0 + wm * 64 + mi * 16 + rw + r;
                float v[4];
                float mx = -1e30f;
#pragma unroll
                for (int ni = 0; ni < 4; ++ni) {
                    v[ni] = acc[mi][ni][r] + bv[ni];
                    int col = ncol0 + wn * 64 + ni * 16 + lr;
                    if constexpr (EPI == 3)
                        Cbf[(size_t)grow * N + col] = f2bf(v[ni]);
                    else
                        Cf[(size_t)grow * N + col] = v[ni];
                    mx = fmaxf(mx, v[ni]);
                }
#pragma unroll
                for (int d = 1; d <= 8; d <<= 1) mx = fmaxf(mx, __shfl_xor(mx, d));
                float ssum = 0.f;
#pragma unroll
                for (int ni = 0; ni < 4; ++ni) ssum += __expf(v[ni] - mx);
#pragma unroll
                for (int d = 1; d <= 8; d <<= 1) ssum += __shfl_xor(ssum, d);
                if (lr == 0) {
                    int lrow = wm * 64 + mi * 16 + rw + r;
                    part_m[wn][lrow] = mx;
                    part_s[wn][lrow] = ssum;
                }
            }
        }
        __syncthreads();
        if (tid < 128) {
            float m0v = part_m[0][tid], m1v = part_m[1][tid];
            float mm = fmaxf(m0v, m1v);
            float ssum = part_s[0][tid] * __expf(m0v - mm) + part_s[1][tid] * __expf(m1v - mm);
            int grow = mrow0 + tid;
            pm[(size_t)grow * NTILE_N + bx] = mm;
            ps[(size_t)grow * NTILE_N + bx] = ssum;
        }
    }
}

// ---------------- LSTM scan (r15-proven, unchanged) ---------------
__global__ __launch_bounds__(512, 2)
void k_lstm_scan(const float* __restrict__ xpartT, const float* __restrict__ Whh,
                 const float* __restrict__ h0, const float* __restrict__ c0,
                 float* __restrict__ hTA, float* __restrict__ hTB,
                 float* __restrict__ Hall, unsigned short* __restrict__ catbuf,
                 float* __restrict__ hf, float* __restrict__ cf,
                 int* __restrict__ cnt) {
    __shared__ __align__(16) float h_lds[BB * 8 * 17 * 4];   // 69.6 KB

    const int tid = threadIdx.x;
    const int jl = tid >> 8;             // 0..1
    const int bq = (tid >> 4) & 15;      // handles b = bq, bq+16
    const int ks = tid & 15;             // k-slice: cols ks*32 .. ks*32+31
    const int jj = blockIdx.x * 2 + jl;

    f32x4 wreg[4][8];
#pragma unroll
    for (int g = 0; g < 4; ++g) {
        const float* wp = Whh + (size_t)(g * DH + jj) * DH + ks * 32;
#pragma unroll
        for (int r = 0; r < 8; ++r)
            wreg[g][r] = *(const f32x4*)(wp + r * 4);
    }

    float creg0 = c0[(size_t)bq * DH + jj];
    float creg1 = c0[(size_t)(bq + 16) * DH + jj];

    float xg0a = 0.f, xg1a = 0.f, xg2a = 0.f, xg3a = 0.f;
    float xg0b = 0.f, xg1b = 0.f, xg2b = 0.f, xg3b = 0.f;
    if (ks == 0) {
        const float* xt = xpartT;
        xg0a = xt[(size_t)(0 * DH + jj) * NROWS + bq];
        xg1a = xt[(size_t)(1 * DH + jj) * NROWS + bq];
        xg2a = xt[(size_t)(2 * DH + jj) * NROWS + bq];
        xg3a = xt[(size_t)(3 * DH + jj) * NROWS + bq];
        xg0b = xt[(size_t)(0 * DH + jj) * NROWS + bq + 16];
        xg1b = xt[(size_t)(1 * DH + jj) * NROWS + bq + 16];
        xg2b = xt[(size_t)(2 * DH + jj) * NROWS + bq + 16];
        xg3b = xt[(size_t)(3 * DH + jj) * NROWS + bq + 16];
    }

    for (int t = 0; t < TT; ++t) {
        const float* hR = (t == 0) ? h0 : ((t & 1) ? hTA : hTB);
        {
            f32x4 v[8];
#pragma unroll
            for (int q = 0; q < 8; ++q)
                asm volatile("global_load_dwordx4 %0, %1, off sc0 sc1"
                             : "=&v"(v[q]) : "v"(hR + (q * 512 + tid) * 4));
            asm volatile("s_waitcnt vmcnt(4)" ::: "memory");
            __builtin_amdgcn_sched_barrier(0);
#pragma unroll
            for (int q = 0; q < 4; ++q) {
                int f = q * 512 + tid;
                int b2 = f >> 7;
                int ks2 = (f & 127) >> 3;
                int r2 = f & 7;
                *(f32x4*)&h_lds[((b2 * 8 + r2) * 17 + ks2) * 4] = v[q];
            }
            asm volatile("s_waitcnt vmcnt(0)" ::: "memory");
            __builtin_amdgcn_sched_barrier(0);
#pragma unroll
            for (int q = 4; q < 8; ++q) {
                int f = q * 512 + tid;
                int b2 = f >> 7;
                int ks2 = (f & 127) >> 3;
                int r2 = f & 7;
                *(f32x4*)&h_lds[((b2 * 8 + r2) * 17 + ks2) * 4] = v[q];
            }
        }
        __syncthreads();

        float a0a = 0.f, a1a = 0.f, a2a = 0.f, a3a = 0.f;
        float a0b = 0.f, a1b = 0.f, a2b = 0.f, a3b = 0.f;
#pragma unroll
        for (int r = 0; r < 8; ++r) {
            f32x4 ha = *(const f32x4*)&h_lds[((bq * 8 + r) * 17 + ks) * 4];
            f32x4 hb = *(const f32x4*)&h_lds[(((bq + 16) * 8 + r) * 17 + ks) * 4];
            a0a += wreg[0][r][0] * ha[0] + wreg[0][r][1] * ha[1]
                 + wreg[0][r][2] * ha[2] + wreg[0][r][3] * ha[3];
            a1a += wreg[1][r][0] * ha[0] + wreg[1][r][1] * ha[1]
                 + wreg[1][r][2] * ha[2] + wreg[1][r][3] * ha[3];
            a2a += wreg[2][r][0] * ha[0] + wreg[2][r][1] * ha[1]
                 + wreg[2][r][2] * ha[2] + wreg[2][r][3] * ha[3];
            a3a += wreg[3][r][0] * ha[0] + wreg[3][r][1] * ha[1]
                 + wreg[3][r][2] * ha[2] + wreg[3][r][3] * ha[3];
            a0b += wreg[0][r][0] * hb[0] + wreg[0][r][1] * hb[1]
                 + wreg[0][r][2] * hb[2] + wreg[0][r][3] * hb[3];
            a1b += wreg[1][r][0] * hb[0] + wreg[1][r][1] * hb[1]
                 + wreg[1][r][2] * hb[2] + wreg[1][r][3] * hb[3];
            a2b += wreg[2][r][0] * hb[0] + wreg[2][r][1] * hb[1]
                 + wreg[2][r][2] * hb[2] + wreg[2][r][3] * hb[3];
            a3b += wreg[3][r][0] * hb[0] + wreg[3][r][1] * hb[1]
                 + wreg[3][r][2] * hb[2] + wreg[3][r][3] * hb[3];
        }
#pragma unroll
        for (int d = 1; d <= 8; d <<= 1) {
            a0a += __shfl_xor(a0a, d); a1a += __shfl_xor(a1a, d);
            a2a += __shfl_xor(a2a, d); a3a += __shfl_xor(a3a, d);
            a0b += __shfl_xor(a0b, d); a1b += __shfl_xor(a1b, d);
            a2b += __shfl_xor(a2b, d); a3b += __shfl_xor(a3b, d);
        }

        if (ks == 0) {
            float* wb = (t & 1) ? hTB : hTA;
#pragma unroll
            for (int bh = 0; bh < 2; ++bh) {
                int b = bh ? bq + 16 : bq;
                float gi = (bh ? a0b : a0a) + (bh ? xg0b : xg0a);
                float gf = (bh ? a1b : a1a) + (bh ? xg1b : xg1a);
                float gg = (bh ? a2b : a2a) + (bh ? xg2b : xg2a);
                float go = (bh ? a3b : a3a) + (bh ? xg3b : xg3a);
                float si = 1.f / (1.f + __expf(-gi));
                float sf = 1.f / (1.f + __expf(-gf));
                float tg = tanhf(gg);
                float so = 1.f / (1.f + __expf(-go));
                float cc = bh ? creg1 : creg0;
                cc = sf * cc + si * tg;
                float hn = so * tanhf(cc);
                if (bh) creg1 = cc; else creg0 = cc;

                coh_store(&wb[(size_t)b * DH + jj], hn);
                int row = t * BB + b;
                Hall[(size_t)row * DH + jj] = hn;
                catbuf[(size_t)row * 1024 + jj] = f2bf(hn);
                if (t == TT - 1) {
                    hf[(size_t)b * DH + jj] = hn;
                    cf[(size_t)b * DH + jj] = cc;
                }
            }
        }

        __syncthreads();
        if (tid == 0) {
            asm volatile("s_waitcnt vmcnt(0)" ::: "memory");
            __hip_atomic_fetch_add(&cnt[t * (NLEAF * 16) + (blockIdx.x & (NLEAF - 1)) * 16], 1,
                                   __ATOMIC_RELAXED, __HIP_MEMORY_SCOPE_AGENT);
        }
        if (ks == 0 && t + 1 < TT) {
            const float* xt = xpartT + (size_t)(t + 1) * BB;
            xg0a = xt[(size_t)(0 * DH + jj) * NROWS + bq];
            xg1a = xt[(size_t)(1 * DH + jj) * NROWS + bq];
            xg2a = xt[(size_t)(2 * DH + jj) * NROWS + bq];
            xg3a = xt[(size_t)(3 * DH + jj) * NROWS + bq];
            xg0b = xt[(size_t)(0 * DH + jj) * NROWS + bq + 16];
            xg1b = xt[(size_t)(1 * DH + jj) * NROWS + bq + 16];
            xg2b = xt[(size_t)(2 * DH + jj) * NROWS + bq + 16];
            xg3b = xt[(size_t)(3 * DH + jj) * NROWS + bq + 16];
        }
        if (tid < NLEAF) {
            while (__hip_atomic_load(&cnt[t * (NLEAF * 16) + tid * 16], __ATOMIC_RELAXED,
                                     __HIP_MEMORY_SCOPE_AGENT) < LEAF_TARGET) {
            }
        }
        __syncthreads();
    }
}

// ---------------- attention: scores -> softmax -> wctx (per (b, 4 t's)) ----------------
__global__ __launch_bounds__(256)
void k_attn(const float* __restrict__ Hall, const float* __restrict__ ctx,
            unsigned short* __restrict__ catbuf) {
    __shared__ float h4[4][DH];
    __shared__ float p_lds[4][SS];
    __shared__ float l_lds[4];

    const int tid = threadIdx.x;
    const int b = blockIdx.x & 31;
    const int tg = blockIdx.x >> 5;

    for (int i = tid; i < 4 * DH / 4; i += 256) {
        int e = i * 4;
        int ti = e >> 9, k = e & 511;
        float4 v = *(const float4*)(Hall + ((size_t)((tg * 4 + ti) * BB + b)) * DH + k);
        h4[ti][k + 0] = v.x; h4[ti][k + 1] = v.y; h4[ti][k + 2] = v.z; h4[ti][k + 3] = v.w;
    }
    __syncthreads();

    {
        int s = tid;
        float acc[4] = {0.f, 0.f, 0.f, 0.f};
        const float4* cp = (const float4*)(ctx + ((size_t)b * SS + s) * DH);
        for (int kc = 0; kc < DH / 4; ++kc) {
            float4 cv = cp[kc];
#pragma unroll
            for (int i = 0; i < 4; ++i) {
                float4 hv = *(const float4*)&h4[i][kc * 4];
                acc[i] += cv.x * hv.x + cv.y * hv.y + cv.z * hv.z + cv.w * hv.w;
            }
        }
#pragma unroll
        for (int i = 0; i < 4; ++i) p_lds[i][s] = acc[i];
    }
    __syncthreads();

    {
        int w = tid >> 6, l = tid & 63;
        float v0 = p_lds[w][l], v1 = p_lds[w][l + 64];
        float v2 = p_lds[w][l + 128], v3 = p_lds[w][l + 192];
        float mx = fmaxf(fmaxf(v0, v1), fmaxf(v2, v3));
        for (int d = 1; d < 64; d <<= 1) mx = fmaxf(mx, __shfl_xor(mx, d));
        float e0 = __expf(v0 - mx), e1 = __expf(v1 - mx);
        float e2 = __expf(v2 - mx), e3 = __expf(v3 - mx);
        float ssum = e0 + e1 + e2 + e3;
        for (int d = 1; d < 64; d <<= 1) ssum += __shfl_xor(ssum, d);
        p_lds[w][l] = e0; p_lds[w][l + 64] = e1;
        p_lds[w][l + 128] = e2; p_lds[w][l + 192] = e3;
        if (l == 0) l_lds[w] = ssum;
    }
    __syncthreads();

    {
        int d0 = tid * 2;
        float accx[4], accy[4];
#pragma unroll
        for (int i = 0; i < 4; ++i) { accx[i] = 0.f; accy[i] = 0.f; }
        const float* cb = ctx + (size_t)b * SS * DH + d0;
        for (int s = 0; s < SS; ++s) {
            float2 cv = *(const float2*)(cb + (size_t)s * DH);
#pragma unroll
            for (int i = 0; i < 4; ++i) {
                float p = p_lds[i][s];
                accx[i] += p * cv.x;
                accy[i] += p * cv.y;
            }
        }
#pragma unroll
        for (int i = 0; i < 4; ++i) {
            float inv = 1.f / l_lds[i];
            int row = (tg * 4 + i) * BB + b;
            unsigned pack = (unsigned)f2bf(accx[i] * inv) | ((unsigned)f2bf(accy[i] * inv) << 16);
            *(unsigned*)&catbuf[(size_t)row * 1024 + DH + d0] = pack;
        }
    }
}

// ---------------- fused lse + subtract (one block per row) ----------------
// BF16IN: logits stored bf16 in Lbf (halved read traffic); else fp32 in logp.
template <bool BF16IN>
__global__ __launch_bounds__(256)
void k_lsesub(float* __restrict__ logp, const unsigned short* __restrict__ Lbf,
              const float* __restrict__ pm, const float* __restrict__ ps, int nt) {
    __shared__ float sL;
    const int row = blockIdx.x;
    const int tid = threadIdx.x;
    if (tid < 64) {
        const float* pmr = pm + (size_t)row * nt;
        const float* psr = ps + (size_t)row * nt;
        float m = -1e30f;
        for (int i = tid; i < nt; i += 64) m = fmaxf(m, pmr[i]);
        for (int d = 1; d < 64; d <<= 1) m = fmaxf(m, __shfl_xor(m, d));
        float s = 0.f;
        for (int i = tid; i < nt; i += 64) s += psr[i] * __expf(pmr[i] - m);
        for (int d = 1; d < 64; d <<= 1) s += __shfl_xor(s, d);
        if (tid == 0) sL = m + logf(s);
    }
    __syncthreads();
    float L = sL;
    if constexpr (BF16IN) {
        const ushort8v* src = (const ushort8v*)(Lbf + (size_t)row * VV);
        float4* dst = (float4*)(logp + (size_t)row * VV);
        for (int i = tid; i < VV / 8; i += 256) {
            ushort8v v = src[i];
            float4 o0, o1;
            o0.x = bf2f((unsigned short)v[0]) - L;
            o0.y = bf2f((unsigned short)v[1]) - L;
            o0.z = bf2f((unsigned short)v[2]) - L;
            o0.w = bf2f((unsigned short)v[3]) - L;
            o1.x = bf2f((unsigned short)v[4]) - L;
            o1.y = bf2f((unsigned short)v[5]) - L;
            o1.z = bf2f((unsigned short)v[6]) - L;
            o1.w = bf2f((unsigned short)v[7]) - L;
            dst[i * 2] = o0;
            dst[i * 2 + 1] = o1;
        }
    } else {
        float4* p = (float4*)(logp + (size_t)row * VV);
        for (int i = tid; i < VV / 4; i += 256) {
            float4 v = p[i];
            v.x -= L; v.y -= L; v.z -= L; v.w -= L;
            p[i] = v;
        }
    }
}

// ---------------- host launch ----------------
extern "C" void kernel_launch(void* const* d_in, const int* in_sizes, int n_in,
                              void* d_out, int out_size, void* d_ws, size_t ws_size,
                              hipStream_t stream) {
    const int*   xseq  = (const int*)d_in[0];
    const float* h0    = (const float*)d_in[1];
    const float* c0    = (const float*)d_in[2];
    const float* ctx   = (const float*)d_in[3];
    const float* emb   = (const float*)d_in[4];
    const float* Wih   = (const float*)d_in[5];
    const float* Whh   = (const float*)d_in[6];
    const float* bih   = (const float*)d_in[7];
    const float* bhh   = (const float*)d_in[8];
    const float* Wattn = (const float*)d_in[9];
    const float* Wout  = (const float*)d_in[10];
    const float* bout  = (const float*)d_in[11];
    float* out = (float*)d_out;

    char* wptr = (char*)d_ws;
    auto carve = [&](size_t bytes) {
        char* p = wptr;
        wptr += (bytes + 255) & ~(size_t)255;
        return p;
    };
    float*          xpartT  = (float*)carve((size_t)NROWS * G4 * 4);
    float*          Hall    = (float*)carve((size_t)NROWS * DH * 4);
    unsigned short* catbf   = (unsigned short*)carve((size_t)NROWS * 1024 * 2);
    unsigned short* outsbf  = (unsigned short*)carve((size_t)NROWS * DH * 2);
    unsigned short* ehi     = (unsigned short*)carve((size_t)NROWS * DH * 2);
    unsigned short* elo     = (unsigned short*)carve((size_t)NROWS * DH * 2);
    unsigned short* Wihhi   = (unsigned short*)carve((size_t)G4 * DH * 2);
    unsigned short* Wihlo   = (unsigned short*)carve((size_t)G4 * DH * 2);
    unsigned short* Wattnbf = (unsigned short*)carve((size_t)DH * 1024 * 2);
    unsigned short* Woutbf  = (unsigned short*)carve((size_t)VV * DH * 2);
    float*          hTA     = (float*)carve((size_t)BB * DH * 4);
    float*          hTB     = (float*)carve((size_t)BB * DH * 4);
    int*            cnt     = (int*)carve((size_t)TT * NLEAF * 16 * 4);
    float*          pm      = (float*)carve((size_t)NROWS * NTILE_N * 4);
    float*          ps      = (float*)carve((size_t)NROWS * NTILE_N * 4);
    // optional bf16 logits buffer (131 MB) -- only if workspace allows
    char* mark = wptr;
    unsigned short* Lbf = (unsigned short*)carve((size_t)NROWS * VV * 2);
    bool use_bf16_logits = ((size_t)(wptr - (char*)d_ws) <= ws_size);
    if (!use_bf16_logits) { wptr = mark; Lbf = nullptr; }

    // prep
    k_convert_bf16<<<256, 256, 0, stream>>>(Wattn, Wattnbf, DH * 1024 / 4);
    k_convert_bf16<<<2048, 256, 0, stream>>>(Wout, Woutbf, VV * DH / 4);
    k_convert_hl<<<512, 256, 0, stream>>>(Wih, Wihhi, Wihlo, G4 * DH / 4);
    k_gather_embed_hl<<<NROWS, 128, 0, stream>>>(xseq, emb, ehi, elo, cnt);

    // x_part^T = (e @ W_ih^T + b_ih + b_hh)^T  -- hi/lo bf16 MFMA (~fp32 accuracy)
    k_mfma_xpart<<<dim3(16, 16), 256, 0, stream>>>(
        ehi, elo, Wihhi, Wihlo, NROWS, G4, DH, bih, bhh, xpartT);

    // sequential LSTM scan (cooperative; register-W, 32-leaf spin barrier)
    {
        const float* a0 = xpartT; const float* a1 = Whh;
        const float* a2 = h0;     const float* a3 = c0;
        float* a4 = hTA; float* a5 = hTB; float* a6 = Hall;
        unsigned short* a7 = catbf;
        float* a8 = out + (size_t)NROWS * VV;           // hf
        float* a9 = a8 + BB * DH;                       // cf
        int* a10 = cnt;
        void* args[] = {&a0, &a1, &a2, &a3, &a4, &a5, &a6, &a7, &a8, &a9, &a10};
        hipLaunchCooperativeKernel((const void*)k_lstm_scan, dim3(NBLK_SCAN), dim3(512),
                                   args, 0, stream);
    }

    // attention (parallel over all t,b)
    k_attn<<<512, 256, 0, stream>>>(Hall, ctx, catbf);

    // outs = tanh(cat @ W_attn^T)  -> bf16
    k_mfma_gemm<1><<<dim3(4, 16), 256, 0, stream>>>(
        catbf, Wattnbf, NROWS, DH, 1024, nullptr, nullptr, outsbf, nullptr, nullptr);

    // logits = outs @ W_out^T + b_out (+ softmax partials); XCD-swizzled 1D grid
    if (use_bf16_logits) {
        k_mfma_gemm<3><<<NTILE_N * NTILE_M, 256, 0, stream>>>(
            outsbf, Woutbf, NROWS, VV, DH, bout, nullptr, Lbf, pm, ps);
        k_lsesub<true><<<NROWS, 256, 0, stream>>>(out, Lbf, pm, ps, NTILE_N);
    } else {
        k_mfma_gemm<2><<<NTILE_N * NTILE_M, 256, 0, stream>>>(
            outsbf, Woutbf, NROWS, VV, DH, bout, out, nullptr, pm, ps);
        k_lsesub<false><<<NROWS, 256, 0, stream>>>(out, nullptr, pm, ps, NTILE_N);
    }
}